// Round 4
// baseline (363.932 us; speedup 1.0000x reference)
//
#include <hip/hip_runtime.h>

typedef unsigned short u16;
typedef __bf16 bf16x8 __attribute__((ext_vector_type(8)));
typedef float f32x4 __attribute__((ext_vector_type(4)));

__device__ __forceinline__ u16 f2bf(float f) {
    union { float f; unsigned int i; } v; v.f = f;
    unsigned int x = v.i;
    x += 0x7fffu + ((x >> 16) & 1u);   // round-to-nearest-even
    return (u16)(x >> 16);
}

// ---------------------------------------------------------------------------
// Kernel 1: qkv = x @ w_qkv^T  (M=4096, N=3072, K=1024), fp32 inputs,
// bf16 conversion fused into LDS staging, RoPE fused in epilogue.
// 128x128 block tile, 4 waves as 2x2 of 64x64 wave tiles, 4x4 of 16x16x32.
// Writes Q[b,h,t,d] (bf16, parked in d_out, dead before outproj's fp32 store),
// K[b,h,t,d], V^T[b,h,d,t]. RoPE partner (d^32) = acc[mi][ni^2], same lane.
// ---------------------------------------------------------------------------
__global__ __launch_bounds__(256, 2)
void qkv_rope_kernel(const float* __restrict__ X, const float* __restrict__ W,
                     const float* __restrict__ Cos, const float* __restrict__ Sin,
                     u16* __restrict__ Qo, u16* __restrict__ Ko, u16* __restrict__ Vo)
{
    __shared__ __align__(16) u16 As[128][72];  // +8 pad: 144B row stride
    __shared__ __align__(16) u16 Bs[128][72];
    const int tid  = threadIdx.x;
    const int lane = tid & 63, wave = tid >> 6;
    const int l15  = lane & 15, q4 = lane >> 4;
    const int wm = (wave >> 1) * 64, wn = (wave & 1) * 64;
    const int m0 = blockIdx.y * 128, n0 = blockIdx.x * 128;

    f32x4 acc[4][4];
    #pragma unroll
    for (int i = 0; i < 4; i++)
        #pragma unroll
        for (int j = 0; j < 4; j++) { f32x4 z = {}; acc[i][j] = z; }

    for (int k0 = 0; k0 < 1024; k0 += 64) {
        __syncthreads();
        #pragma unroll
        for (int i = 0; i < 8; i++) {
            int c = tid + i * 256;            // 2048 float4-chunks per matrix
            int row = c >> 4, col = (c & 15) * 4;
            float4 xv = *(const float4*)(X + (size_t)(m0 + row) * 1024 + k0 + col);
            float4 wv = *(const float4*)(W + (size_t)(n0 + row) * 1024 + k0 + col);
            ushort4 xa, wa;
            xa.x = f2bf(xv.x); xa.y = f2bf(xv.y); xa.z = f2bf(xv.z); xa.w = f2bf(xv.w);
            wa.x = f2bf(wv.x); wa.y = f2bf(wv.y); wa.z = f2bf(wv.z); wa.w = f2bf(wv.w);
            *(ushort4*)&As[row][col] = xa;
            *(ushort4*)&Bs[row][col] = wa;
        }
        __syncthreads();
        #pragma unroll
        for (int ks = 0; ks < 2; ks++) {
            bf16x8 af[4], bfr[4];
            #pragma unroll
            for (int i = 0; i < 4; i++) {
                af[i]  = *(const bf16x8*)&As[wm + i * 16 + l15][ks * 32 + q4 * 8];
                bfr[i] = *(const bf16x8*)&Bs[wn + i * 16 + l15][ks * 32 + q4 * 8];
            }
            #pragma unroll
            for (int mi = 0; mi < 4; mi++)
                #pragma unroll
                for (int ni = 0; ni < 4; ni++)
                    acc[mi][ni] = __builtin_amdgcn_mfma_f32_16x16x32_bf16(
                        af[mi], bfr[ni], acc[mi][ni], 0, 0, 0);
        }
    }

    // Epilogue: C/D layout col=lane&15, row=(lane>>4)*4+reg
    #pragma unroll
    for (int mi = 0; mi < 4; mi++) {
        #pragma unroll
        for (int r = 0; r < 4; r++) {
            int row = m0 + wm + mi * 16 + q4 * 4 + r;     // global m = b*T + t
            int b = row >> 11, t = row & 2047;
            #pragma unroll
            for (int ni = 0; ni < 4; ni++) {
                int col = n0 + wn + ni * 16 + l15;        // global f in [0,3072)
                float v = acc[mi][ni][r];
                int sec = col >> 10;                      // 0=q 1=k 2=v
                int hh  = (col >> 6) & 15;
                int d   = col & 63;
                if (sec < 2) {
                    float cs = Cos[t * 64 + d];
                    float sn = Sin[t * 64 + d];
                    float partner = acc[mi][ni ^ 2][r];   // col ^ 32, same lane
                    float rot = (d < 32) ? -partner : partner;
                    v = v * cs + rot * sn;
                    u16* dst = (sec == 0) ? Qo : Ko;
                    dst[(((size_t)(b * 16 + hh)) * 2048 + t) * 64 + d] = f2bf(v);
                } else {
                    // V stored transposed per head: [b,h,d,t]
                    Vo[(((size_t)(b * 16 + hh)) * 64 + d) * 2048 + t] = f2bf(v);
                }
            }
        }
    }
}

// ---------------------------------------------------------------------------
// Kernel 2: causal flash attention over bf16 intermediates.
// Grid = 512 blocks = 16 q-tiles x 32 (b,h); wave w owns q-rows [w*32,w*32+32).
// ---------------------------------------------------------------------------
__global__ __launch_bounds__(256, 2)
void attn_kernel(const u16* __restrict__ Q, const u16* __restrict__ Kg,
                 const u16* __restrict__ Vt, u16* __restrict__ Oh)
{
    __shared__ __align__(16) u16    Ks[64][72];
    __shared__ __align__(16) u16    Vs[64][72];
    __shared__ __align__(16) __bf16 Ps[4][32][72];

    const int bx = blockIdx.x;
    const int qt = bx & 15;            // q-tile
    const int bh = bx >> 4;            // 0..31
    const int b = bh >> 4, h = bh & 15;
    const int tid = threadIdx.x, wave = tid >> 6, lane = tid & 63;
    const int l15 = lane & 15, q4 = lane >> 4;

    const size_t head_off = (size_t)bh * 2048 * 64;
    const u16* Qb = Q  + head_off;
    const u16* Kb = Kg + head_off;
    const u16* Vb = Vt + head_off;     // [d][t] layout per head

    const int q0 = qt * 128;
    const int qw = q0 + wave * 32;

    // Q fragments in registers: A[m=l15+16*mi][k=q4*8+j+32*ks]
    bf16x8 qf[2][2];
    #pragma unroll
    for (int mi = 0; mi < 2; mi++)
        #pragma unroll
        for (int ks = 0; ks < 2; ks++)
            qf[mi][ks] = *(const bf16x8*)(Qb + (size_t)(qw + mi * 16 + l15) * 64 + ks * 32 + q4 * 8);

    f32x4 o[2][4];
    float mst[2][4], lst[2][4];
    #pragma unroll
    for (int mi = 0; mi < 2; mi++) {
        #pragma unroll
        for (int ni = 0; ni < 4; ni++) { f32x4 z = {}; o[mi][ni] = z; }
        #pragma unroll
        for (int r = 0; r < 4; r++) { mst[mi][r] = -1e30f; lst[mi][r] = 0.f; }
    }

    const int nkv = qt * 2 + 2;        // kv tiles with k0 <= q0+127 (block-uniform)
    for (int it = 0; it < nkv; it++) {
        const int k0 = it * 64;
        __syncthreads();               // protect Ks/Vs from previous iteration's reads
        #pragma unroll
        for (int i = 0; i < 2; i++) {
            int c = tid + i * 256;     // 512 16B-chunks per tile
            int row = c >> 3, cc = (c & 7) * 8;
            *(uint4*)&Ks[row][cc] = *(const uint4*)(Kb + (size_t)(k0 + row) * 64 + cc);
            *(uint4*)&Vs[row][cc] = *(const uint4*)(Vb + (size_t)row * 2048 + k0 + cc);
        }
        __syncthreads();

        // S = Q K^T  (contraction over d=64)
        f32x4 s[2][4];
        #pragma unroll
        for (int mi = 0; mi < 2; mi++)
            #pragma unroll
            for (int ni = 0; ni < 4; ni++) { f32x4 z = {}; s[mi][ni] = z; }
        #pragma unroll
        for (int ks = 0; ks < 2; ks++) {
            bf16x8 kf[4];
            #pragma unroll
            for (int ni = 0; ni < 4; ni++)
                kf[ni] = *(const bf16x8*)&Ks[ni * 16 + l15][ks * 32 + q4 * 8];
            #pragma unroll
            for (int mi = 0; mi < 2; mi++)
                #pragma unroll
                for (int ni = 0; ni < 4; ni++)
                    s[mi][ni] = __builtin_amdgcn_mfma_f32_16x16x32_bf16(
                        qf[mi][ks], kf[ni], s[mi][ni], 0, 0, 0);
        }

        // scale + causal mask + online softmax; rows on (mi,q4,r), cols on (ni,l15)
        #pragma unroll
        for (int mi = 0; mi < 2; mi++) {
            #pragma unroll
            for (int r = 0; r < 4; r++) {
                const int tq = qw + mi * 16 + q4 * 4 + r;
                float rm = -1e30f;
                #pragma unroll
                for (int ni = 0; ni < 4; ni++) {
                    int tk = k0 + ni * 16 + l15;
                    float sv = s[mi][ni][r] * 0.125f;
                    if (tk > tq) sv = -1e30f;
                    s[mi][ni][r] = sv;
                    rm = fmaxf(rm, sv);
                }
                #pragma unroll
                for (int off = 1; off < 16; off <<= 1)
                    rm = fmaxf(rm, __shfl_xor(rm, off, 64));
                float mnew  = fmaxf(mst[mi][r], rm);
                float alpha = __expf(mst[mi][r] - mnew);
                float rs = 0.f;
                #pragma unroll
                for (int ni = 0; ni < 4; ni++) {
                    float p = __expf(s[mi][ni][r] - mnew);
                    s[mi][ni][r] = p;
                    rs += p;
                }
                #pragma unroll
                for (int off = 1; off < 16; off <<= 1)
                    rs += __shfl_xor(rs, off, 64);
                lst[mi][r] = lst[mi][r] * alpha + rs;
                mst[mi][r] = mnew;
                #pragma unroll
                for (int ni = 0; ni < 4; ni++)
                    o[mi][ni][r] *= alpha;             // per-row rescale
                #pragma unroll
                for (int ni = 0; ni < 4; ni++)
                    Ps[wave][mi * 16 + q4 * 4 + r][ni * 16 + l15] = (__bf16)s[mi][ni][r];
            }
        }

        __syncthreads();   // fence: Ps writes visible before vector reads

        // O += P V  (contraction over kv=64); B-operand rows = V^T rows [d][kv]
        #pragma unroll
        for (int ks = 0; ks < 2; ks++) {
            bf16x8 pa[2], vf[4];
            #pragma unroll
            for (int mi = 0; mi < 2; mi++)
                pa[mi] = *(const bf16x8*)&Ps[wave][mi * 16 + l15][ks * 32 + q4 * 8];
            #pragma unroll
            for (int ni = 0; ni < 4; ni++)
                vf[ni] = *(const bf16x8*)&Vs[ni * 16 + l15][ks * 32 + q4 * 8];
            #pragma unroll
            for (int mi = 0; mi < 2; mi++)
                #pragma unroll
                for (int ni = 0; ni < 4; ni++)
                    o[mi][ni] = __builtin_amdgcn_mfma_f32_16x16x32_bf16(
                        pa[mi], vf[ni], o[mi][ni], 0, 0, 0);
        }
    }

    // Epilogue: O / l, write Oh[b,t,h,d] (= [4096,1024] rows for final GEMM)
    #pragma unroll
    for (int mi = 0; mi < 2; mi++) {
        #pragma unroll
        for (int r = 0; r < 4; r++) {
            int t = qw + mi * 16 + q4 * 4 + r;
            float inv = 1.0f / lst[mi][r];
            #pragma unroll
            for (int ni = 0; ni < 4; ni++) {
                int d = ni * 16 + l15;
                Oh[(((size_t)(b * 2048 + t)) * 16 + h) * 64 + d] = f2bf(o[mi][ni][r] * inv);
            }
        }
    }
}

// ---------------------------------------------------------------------------
// Kernel 3: out = Oh @ w_out^T  (M=4096, N=1024, K=1024).
// A = Oh bf16 (ours), W = w_out fp32 (converted in staging), out FP32.
// ---------------------------------------------------------------------------
__global__ __launch_bounds__(256, 2)
void outproj_kernel(const u16* __restrict__ A, const float* __restrict__ W,
                    float* __restrict__ Cout)
{
    __shared__ __align__(16) u16 As[128][72];
    __shared__ __align__(16) u16 Bs[128][72];
    const int tid  = threadIdx.x;
    const int lane = tid & 63, wave = tid >> 6;
    const int l15  = lane & 15, q4 = lane >> 4;
    const int wm = (wave >> 1) * 64, wn = (wave & 1) * 64;
    const int m0 = blockIdx.y * 128, n0 = blockIdx.x * 128;

    f32x4 acc[4][4];
    #pragma unroll
    for (int i = 0; i < 4; i++)
        #pragma unroll
        for (int j = 0; j < 4; j++) { f32x4 z = {}; acc[i][j] = z; }

    for (int k0 = 0; k0 < 1024; k0 += 64) {
        __syncthreads();
        #pragma unroll
        for (int i = 0; i < 4; i++) {          // A: bf16, 8-elem chunks
            int c = tid + i * 256;
            int row = c >> 3, cc = (c & 7) * 8;
            *(uint4*)&As[row][cc] = *(const uint4*)(A + (size_t)(m0 + row) * 1024 + k0 + cc);
        }
        #pragma unroll
        for (int i = 0; i < 8; i++) {          // W: fp32 -> bf16, 4-elem chunks
            int c = tid + i * 256;
            int row = c >> 4, col = (c & 15) * 4;
            float4 wv = *(const float4*)(W + (size_t)(n0 + row) * 1024 + k0 + col);
            ushort4 wa;
            wa.x = f2bf(wv.x); wa.y = f2bf(wv.y); wa.z = f2bf(wv.z); wa.w = f2bf(wv.w);
            *(ushort4*)&Bs[row][col] = wa;
        }
        __syncthreads();
        #pragma unroll
        for (int ks = 0; ks < 2; ks++) {
            bf16x8 af[4], bfr[4];
            #pragma unroll
            for (int i = 0; i < 4; i++) {
                af[i]  = *(const bf16x8*)&As[wm + i * 16 + l15][ks * 32 + q4 * 8];
                bfr[i] = *(const bf16x8*)&Bs[wn + i * 16 + l15][ks * 32 + q4 * 8];
            }
            #pragma unroll
            for (int mi = 0; mi < 4; mi++)
                #pragma unroll
                for (int ni = 0; ni < 4; ni++)
                    acc[mi][ni] = __builtin_amdgcn_mfma_f32_16x16x32_bf16(
                        af[mi], bfr[ni], acc[mi][ni], 0, 0, 0);
        }
    }

    #pragma unroll
    for (int mi = 0; mi < 4; mi++)
        #pragma unroll
        for (int r = 0; r < 4; r++) {
            int row = m0 + wm + mi * 16 + q4 * 4 + r;
            #pragma unroll
            for (int ni = 0; ni < 4; ni++) {
                int col = n0 + wn + ni * 16 + l15;
                Cout[(size_t)row * 1024 + col] = acc[mi][ni][r];   // FP32 store
            }
        }
}

extern "C" void kernel_launch(void* const* d_in, const int* in_sizes, int n_in,
                              void* d_out, int out_size, void* d_ws, size_t ws_size,
                              hipStream_t stream) {
    (void)in_sizes; (void)n_in; (void)out_size; (void)ws_size;
    const float* x     = (const float*)d_in[0];   // [2,2048,1024] fp32
    const float* cosp  = (const float*)d_in[1];   // [2048,64] fp32
    const float* sinp  = (const float*)d_in[2];   // [2048,64] fp32
    const float* w_qkv = (const float*)d_in[3];   // [3072,1024] fp32
    const float* w_out = (const float*)d_in[4];   // [1024,1024] fp32
    float* out = (float*)d_out;                   // [2,2048,1024] FP32

    const size_t NELEM = (size_t)2 * 2048 * 1024;  // 4,194,304
    // Q (bf16, 8MB) parks in d_out (fp32, 16MB); fully overwritten by outproj.
    u16* Q  = (u16*)d_out;         // [b,h,t,d]
    u16* K  = (u16*)d_ws;          // [b,h,t,d]
    u16* Vt = K  + NELEM;          // [b,h,d,t]
    u16* Oh = Vt + NELEM;          // [b,t,h,d] == [4096,1024]

    qkv_rope_kernel<<<dim3(24, 32), 256, 0, stream>>>(x, w_qkv, cosp, sinp, Q, K, Vt);
    attn_kernel<<<dim3(512), 256, 0, stream>>>(Q, K, Vt, Oh);
    outproj_kernel<<<dim3(8, 32), 256, 0, stream>>>(Oh, w_out, out);
}

// Round 5
// 242.941 us; speedup vs baseline: 1.4980x; 1.4980x over previous
//
#include <hip/hip_runtime.h>

typedef unsigned short u16;
typedef __bf16 bf16x8 __attribute__((ext_vector_type(8)));
typedef float f32x4 __attribute__((ext_vector_type(4)));

__device__ __forceinline__ u16 f2bf(float f) {
    union { float f; unsigned int i; } v; v.f = f;
    unsigned int x = v.i;
    x += 0x7fffu + ((x >> 16) & 1u);   // round-to-nearest-even
    return (u16)(x >> 16);
}

// Async global->LDS 16B copy. LDS dest is wave-uniform base + lane*16.
__device__ __forceinline__ void gl_lds16(const u16* g, u16* l) {
    __builtin_amdgcn_global_load_lds(
        (const __attribute__((address_space(1))) void*)g,
        (__attribute__((address_space(3))) void*)l, 16, 0, 0);
}

// ---------------------------------------------------------------------------
// cvt: fp32 -> bf16, vectorized. Two source ranges in one launch.
// ---------------------------------------------------------------------------
__global__ __launch_bounds__(256, 2)
void cvt_xw_kernel(const float* __restrict__ X, const float* __restrict__ Wq,
                   u16* __restrict__ Xb, u16* __restrict__ Wqb)
{
    const int n1 = 4194304 / 4;   // x chunks
    const int n2 = 3145728 / 4;   // w_qkv chunks
    int i = blockIdx.x * 256 + threadIdx.x;
    const int stride = gridDim.x * 256;
    for (; i < n1 + n2; i += stride) {
        float4 v;
        ushort4* dst;
        if (i < n1) { v = ((const float4*)X)[i];       dst = (ushort4*)Xb + i; }
        else        { v = ((const float4*)Wq)[i - n1]; dst = (ushort4*)Wqb + (i - n1); }
        ushort4 o;
        o.x = f2bf(v.x); o.y = f2bf(v.y); o.z = f2bf(v.z); o.w = f2bf(v.w);
        *dst = o;
    }
}

__global__ __launch_bounds__(256, 2)
void cvt_w_kernel(const float* __restrict__ W, u16* __restrict__ Wb)
{
    int i = blockIdx.x * 256 + threadIdx.x;     // 262144 chunks, grid covers exactly
    float4 v = ((const float4*)W)[i];
    ushort4 o;
    o.x = f2bf(v.x); o.y = f2bf(v.y); o.z = f2bf(v.z); o.w = f2bf(v.w);
    ((ushort4*)Wb)[i] = o;
}

// ---------------------------------------------------------------------------
// Kernel 1: qkv = x @ w_qkv^T (M=4096,N=3072,K=1024), bf16 in, RoPE epilogue.
// m97 pattern: global_load_lds 16B staging into unpadded XOR-swizzled LDS.
// LDS layout: [row][chunk], phys chunk p at row r holds logical chunk p^(r&7).
// ---------------------------------------------------------------------------
__global__ __launch_bounds__(256, 2)
void qkv_rope_kernel(const u16* __restrict__ X, const u16* __restrict__ W,
                     const float* __restrict__ Cos, const float* __restrict__ Sin,
                     u16* __restrict__ Qo, u16* __restrict__ Ko, u16* __restrict__ Vo)
{
    __shared__ __align__(16) u16 As[128 * 64];
    __shared__ __align__(16) u16 Bs[128 * 64];
    const int tid  = threadIdx.x;
    const int lane = tid & 63, wave = tid >> 6;
    const int l15  = lane & 15, q4 = lane >> 4;
    const int wm = (wave >> 1) * 64, wn = (wave & 1) * 64;
    const int m0 = blockIdx.y * 128, n0 = blockIdx.x * 128;
    const int srow = lane >> 3;                  // row within 8-row issue
    const int scol = ((lane & 7) ^ srow) * 8;    // swizzled source column (elements)

    f32x4 acc[4][4];
    #pragma unroll
    for (int i = 0; i < 4; i++)
        #pragma unroll
        for (int j = 0; j < 4; j++) { f32x4 z = {}; acc[i][j] = z; }

    for (int k0 = 0; k0 < 1024; k0 += 64) {
        __syncthreads();
        #pragma unroll
        for (int i = 0; i < 4; i++) {
            int rb = wave * 32 + i * 8;          // wave-uniform row-block base
            gl_lds16(X + (size_t)(m0 + rb + srow) * 1024 + k0 + scol, As + rb * 64);
            gl_lds16(W + (size_t)(n0 + rb + srow) * 1024 + k0 + scol, Bs + rb * 64);
        }
        __syncthreads();
        #pragma unroll
        for (int ks = 0; ks < 2; ks++) {
            const int ch = (((4 * ks + q4) ^ (l15 & 7)) * 8);
            bf16x8 af[4], bfr[4];
            #pragma unroll
            for (int i = 0; i < 4; i++) {
                af[i]  = *(const bf16x8*)&As[(wm + i * 16 + l15) * 64 + ch];
                bfr[i] = *(const bf16x8*)&Bs[(wn + i * 16 + l15) * 64 + ch];
            }
            #pragma unroll
            for (int mi = 0; mi < 4; mi++)
                #pragma unroll
                for (int ni = 0; ni < 4; ni++)
                    acc[mi][ni] = __builtin_amdgcn_mfma_f32_16x16x32_bf16(
                        af[mi], bfr[ni], acc[mi][ni], 0, 0, 0);
        }
    }

    // Epilogue: C/D layout col=lane&15, row=(lane>>4)*4+reg. RoPE fused.
    #pragma unroll
    for (int mi = 0; mi < 4; mi++) {
        #pragma unroll
        for (int r = 0; r < 4; r++) {
            int row = m0 + wm + mi * 16 + q4 * 4 + r;     // global m = b*T + t
            int b = row >> 11, t = row & 2047;
            #pragma unroll
            for (int ni = 0; ni < 4; ni++) {
                int col = n0 + wn + ni * 16 + l15;        // global f in [0,3072)
                float v = acc[mi][ni][r];
                int sec = col >> 10;                      // 0=q 1=k 2=v
                int hh  = (col >> 6) & 15;
                int d   = col & 63;
                if (sec < 2) {
                    float cs = Cos[t * 64 + d];
                    float sn = Sin[t * 64 + d];
                    float partner = acc[mi][ni ^ 2][r];   // col ^ 32, same lane
                    float rot = (d < 32) ? -partner : partner;
                    v = v * cs + rot * sn;
                    u16* dst = (sec == 0) ? Qo : Ko;
                    dst[(((size_t)(b * 16 + hh)) * 2048 + t) * 64 + d] = f2bf(v);
                } else {
                    Vo[(((size_t)(b * 16 + hh)) * 64 + d) * 2048 + t] = f2bf(v);  // [b,h,d,t]
                }
            }
        }
    }
}

// ---------------------------------------------------------------------------
// Kernel 2: causal flash attention. 64 q-rows/block, 2 waves (32 rows each).
// Grid = 1024 blocks (32 q-blocks x 32 bh), longest-qt first (LPT); all
// blocks co-resident (LDS 25 KB -> up to 6/CU). K/V staged via global_load_lds
// into swizzled LDS; mask only on the diagonal tile.
// ---------------------------------------------------------------------------
__global__ __launch_bounds__(128, 2)
void attn_kernel(const u16* __restrict__ Q, const u16* __restrict__ Kg,
                 const u16* __restrict__ Vt, u16* __restrict__ Oh)
{
    __shared__ __align__(16) u16 Ks[64 * 64];
    __shared__ __align__(16) u16 Vs[64 * 64];
    __shared__ __align__(16) __bf16 Ps[2][32][72];

    const int bx = blockIdx.x;
    const int qt = 31 - (bx >> 5);     // longest blocks launch first
    const int bh = bx & 31;
    const int b = bh >> 4, h = bh & 15;
    const int tid = threadIdx.x, wave = tid >> 6, lane = tid & 63;
    const int l15 = lane & 15, q4 = lane >> 4;
    const int srow = lane >> 3;
    const int scol = ((lane & 7) ^ srow) * 8;

    const size_t head_off = (size_t)bh * 2048 * 64;
    const u16* Qb = Q  + head_off;
    const u16* Kb = Kg + head_off;
    const u16* Vb = Vt + head_off;     // [d][t] per head

    const int qw = qt * 64 + wave * 32;

    // Q fragments in registers: A[m=l15+16*mi][k=q4*8+j+32*ks]
    bf16x8 qf[2][2];
    #pragma unroll
    for (int mi = 0; mi < 2; mi++)
        #pragma unroll
        for (int ks = 0; ks < 2; ks++)
            qf[mi][ks] = *(const bf16x8*)(Qb + (size_t)(qw + mi * 16 + l15) * 64 + ks * 32 + q4 * 8);

    f32x4 o[2][4];
    float mst[2][4], lst[2][4];
    #pragma unroll
    for (int mi = 0; mi < 2; mi++) {
        #pragma unroll
        for (int ni = 0; ni < 4; ni++) { f32x4 z = {}; o[mi][ni] = z; }
        #pragma unroll
        for (int r = 0; r < 4; r++) { mst[mi][r] = -1e30f; lst[mi][r] = 0.f; }
    }

    const int nkv = qt + 1;            // kv tiles of 64 (block-uniform)
    for (int it = 0; it < nkv; it++) {
        const int k0 = it * 64;
        __syncthreads();               // protect Ks/Vs from prev iteration reads
        if (wave == 0) {
            #pragma unroll
            for (int i = 0; i < 8; i++)
                gl_lds16(Kb + (size_t)(k0 + i * 8 + srow) * 64 + scol, Ks + i * 8 * 64);
        } else {
            #pragma unroll
            for (int i = 0; i < 8; i++)
                gl_lds16(Vb + (size_t)(i * 8 + srow) * 2048 + k0 + scol, Vs + i * 8 * 64);
        }
        __syncthreads();

        // S = Q K^T
        f32x4 s[2][4];
        #pragma unroll
        for (int mi = 0; mi < 2; mi++)
            #pragma unroll
            for (int ni = 0; ni < 4; ni++) { f32x4 z = {}; s[mi][ni] = z; }
        #pragma unroll
        for (int ks = 0; ks < 2; ks++) {
            const int ch = (((4 * ks + q4) ^ (l15 & 7)) * 8);
            bf16x8 kf[4];
            #pragma unroll
            for (int ni = 0; ni < 4; ni++)
                kf[ni] = *(const bf16x8*)&Ks[(ni * 16 + l15) * 64 + ch];
            #pragma unroll
            for (int mi = 0; mi < 2; mi++)
                #pragma unroll
                for (int ni = 0; ni < 4; ni++)
                    s[mi][ni] = __builtin_amdgcn_mfma_f32_16x16x32_bf16(
                        qf[mi][ks], kf[ni], s[mi][ni], 0, 0, 0);
        }

        const bool diag = (it == qt);  // only tile needing the causal mask

        // scale + (diag) mask + online softmax; rows (mi,q4,r), cols (ni,l15)
        #pragma unroll
        for (int mi = 0; mi < 2; mi++) {
            #pragma unroll
            for (int r = 0; r < 4; r++) {
                const int tq = qw + mi * 16 + q4 * 4 + r;
                float rm = -1e30f;
                #pragma unroll
                for (int ni = 0; ni < 4; ni++) {
                    float sv = s[mi][ni][r] * 0.125f;
                    if (diag && (k0 + ni * 16 + l15 > tq)) sv = -1e30f;
                    s[mi][ni][r] = sv;
                    rm = fmaxf(rm, sv);
                }
                #pragma unroll
                for (int off = 1; off < 16; off <<= 1)
                    rm = fmaxf(rm, __shfl_xor(rm, off, 64));
                float mnew  = fmaxf(mst[mi][r], rm);
                float alpha = __expf(mst[mi][r] - mnew);
                float rs = 0.f;
                #pragma unroll
                for (int ni = 0; ni < 4; ni++) {
                    float p = __expf(s[mi][ni][r] - mnew);
                    s[mi][ni][r] = p;
                    rs += p;
                }
                #pragma unroll
                for (int off = 1; off < 16; off <<= 1)
                    rs += __shfl_xor(rs, off, 64);
                lst[mi][r] = lst[mi][r] * alpha + rs;
                mst[mi][r] = mnew;
                #pragma unroll
                for (int ni = 0; ni < 4; ni++)
                    o[mi][ni][r] *= alpha;
                #pragma unroll
                for (int ni = 0; ni < 4; ni++)
                    Ps[wave][mi * 16 + q4 * 4 + r][ni * 16 + l15] = (__bf16)s[mi][ni][r];
            }
        }

        __syncthreads();   // Ps visible before PV reads

        // O += P V ; B-operand rows = V^T rows [d][kv]
        #pragma unroll
        for (int ks = 0; ks < 2; ks++) {
            const int ch = (((4 * ks + q4) ^ (l15 & 7)) * 8);
            bf16x8 pa[2], vf[4];
            #pragma unroll
            for (int mi = 0; mi < 2; mi++)
                pa[mi] = *(const bf16x8*)&Ps[wave][mi * 16 + l15][ks * 32 + q4 * 8];
            #pragma unroll
            for (int ni = 0; ni < 4; ni++)
                vf[ni] = *(const bf16x8*)&Vs[(ni * 16 + l15) * 64 + ch];
            #pragma unroll
            for (int mi = 0; mi < 2; mi++)
                #pragma unroll
                for (int ni = 0; ni < 4; ni++)
                    o[mi][ni] = __builtin_amdgcn_mfma_f32_16x16x32_bf16(
                        pa[mi], vf[ni], o[mi][ni], 0, 0, 0);
        }
    }

    // Epilogue: O / l -> Oh[b,t,h,d] (= [4096,1024] rows)
    #pragma unroll
    for (int mi = 0; mi < 2; mi++) {
        #pragma unroll
        for (int r = 0; r < 4; r++) {
            int t = qw + mi * 16 + q4 * 4 + r;
            float inv = 1.0f / lst[mi][r];
            #pragma unroll
            for (int ni = 0; ni < 4; ni++) {
                int d = ni * 16 + l15;
                Oh[(((size_t)(b * 2048 + t)) * 16 + h) * 64 + d] = f2bf(o[mi][ni][r] * inv);
            }
        }
    }
}

// ---------------------------------------------------------------------------
// Kernel 3: out = Oh @ w_out^T (M=4096,N=1024,K=1024), fp32 out.
// 128x64 tiles -> 512 blocks (2/CU). Same staging pattern.
// ---------------------------------------------------------------------------
__global__ __launch_bounds__(256, 2)
void outproj_kernel(const u16* __restrict__ A, const u16* __restrict__ W,
                    float* __restrict__ Cout)
{
    __shared__ __align__(16) u16 As[128 * 64];
    __shared__ __align__(16) u16 Bs[64 * 64];
    const int tid  = threadIdx.x;
    const int lane = tid & 63, wave = tid >> 6;
    const int l15  = lane & 15, q4 = lane >> 4;
    const int wm = (wave >> 1) * 64, wn = (wave & 1) * 32;
    const int m0 = blockIdx.y * 128, n0 = blockIdx.x * 64;
    const int srow = lane >> 3;
    const int scol = ((lane & 7) ^ srow) * 8;

    f32x4 acc[4][2];
    #pragma unroll
    for (int i = 0; i < 4; i++)
        #pragma unroll
        for (int j = 0; j < 2; j++) { f32x4 z = {}; acc[i][j] = z; }

    for (int k0 = 0; k0 < 1024; k0 += 64) {
        __syncthreads();
        #pragma unroll
        for (int i = 0; i < 6; i++) {           // 24 issues: 16 A + 8 B
            int id = wave * 6 + i;
            if (id < 16) {
                int rb = id * 8;
                gl_lds16(A + (size_t)(m0 + rb + srow) * 1024 + k0 + scol, As + rb * 64);
            } else {
                int rb = (id - 16) * 8;
                gl_lds16(W + (size_t)(n0 + rb + srow) * 1024 + k0 + scol, Bs + rb * 64);
            }
        }
        __syncthreads();
        #pragma unroll
        for (int ks = 0; ks < 2; ks++) {
            const int ch = (((4 * ks + q4) ^ (l15 & 7)) * 8);
            bf16x8 af[4], bfr[2];
            #pragma unroll
            for (int i = 0; i < 4; i++)
                af[i] = *(const bf16x8*)&As[(wm + i * 16 + l15) * 64 + ch];
            #pragma unroll
            for (int ni = 0; ni < 2; ni++)
                bfr[ni] = *(const bf16x8*)&Bs[(wn + ni * 16 + l15) * 64 + ch];
            #pragma unroll
            for (int mi = 0; mi < 4; mi++)
                #pragma unroll
                for (int ni = 0; ni < 2; ni++)
                    acc[mi][ni] = __builtin_amdgcn_mfma_f32_16x16x32_bf16(
                        af[mi], bfr[ni], acc[mi][ni], 0, 0, 0);
        }
    }

    #pragma unroll
    for (int mi = 0; mi < 4; mi++)
        #pragma unroll
        for (int r = 0; r < 4; r++) {
            int row = m0 + wm + mi * 16 + q4 * 4 + r;
            #pragma unroll
            for (int ni = 0; ni < 2; ni++) {
                int col = n0 + wn + ni * 16 + l15;
                Cout[(size_t)row * 1024 + col] = acc[mi][ni][r];
            }
        }
}

extern "C" void kernel_launch(void* const* d_in, const int* in_sizes, int n_in,
                              void* d_out, int out_size, void* d_ws, size_t ws_size,
                              hipStream_t stream) {
    (void)in_sizes; (void)n_in; (void)out_size; (void)ws_size;
    const float* x     = (const float*)d_in[0];   // [2,2048,1024] fp32
    const float* cosp  = (const float*)d_in[1];   // [2048,64] fp32
    const float* sinp  = (const float*)d_in[2];   // [2048,64] fp32
    const float* w_qkv = (const float*)d_in[3];   // [3072,1024] fp32
    const float* w_out = (const float*)d_in[4];   // [1024,1024] fp32
    float* out = (float*)d_out;                   // [2,2048,1024] fp32

    const size_t NELEM = (size_t)2 * 2048 * 1024;  // 4,194,304
    // d_out (16.8 MB fp32) double-duty: Q bf16 in lower half, X bf16 in upper.
    // Both dead before outproj overwrites all of d_out.
    u16* Q   = (u16*)d_out;            // [b,h,t,d]
    u16* Xb  = (u16*)d_out + NELEM;    // [4096,1024] bf16
    // ws (25.2 MB, same footprint as round 4):
    u16* K   = (u16*)d_ws;             // [b,h,t,d]
    u16* Vt  = K + NELEM;              // [b,h,d,t]
    u16* Oh  = Vt + NELEM;             // [b,t,h,d]
    u16* Wqb = Oh;                     // w_qkv bf16 (3.15M el) — dead before attn writes Oh
    u16* Wob = K;                      // w_out bf16 (1.05M el) — written after attn (K dead)

    cvt_xw_kernel<<<7168, 256, 0, stream>>>(x, w_qkv, Xb, Wqb);
    qkv_rope_kernel<<<dim3(24, 32), 256, 0, stream>>>(Xb, Wqb, cosp, sinp, Q, K, Vt);
    attn_kernel<<<1024, 128, 0, stream>>>(Q, K, Vt, Oh);
    cvt_w_kernel<<<1024, 256, 0, stream>>>(w_out, Wob);
    outproj_kernel<<<dim3(16, 32), 256, 0, stream>>>(Oh, Wob, out);
}

// Round 6
// 220.318 us; speedup vs baseline: 1.6519x; 1.1027x over previous
//
#include <hip/hip_runtime.h>

typedef unsigned short u16;
typedef __bf16 bf16x8 __attribute__((ext_vector_type(8)));
typedef float f32x4 __attribute__((ext_vector_type(4)));

__device__ __forceinline__ u16 f2bf(float f) {
    union { float f; unsigned int i; } v; v.f = f;
    unsigned int x = v.i;
    x += 0x7fffu + ((x >> 16) & 1u);   // round-to-nearest-even
    return (u16)(x >> 16);
}

// Async global->LDS 16B copy. LDS dest is wave-uniform base + lane*16.
__device__ __forceinline__ void gl_lds16(const u16* g, u16* l) {
    __builtin_amdgcn_global_load_lds(
        (const __attribute__((address_space(1))) void*)g,
        (__attribute__((address_space(3))) void*)l, 16, 0, 0);
}

// ---------------------------------------------------------------------------
// cvt: fp32 -> bf16, vectorized.
// ---------------------------------------------------------------------------
__global__ __launch_bounds__(256, 2)
void cvt_xw_kernel(const float* __restrict__ X, const float* __restrict__ Wq,
                   u16* __restrict__ Xb, u16* __restrict__ Wqb)
{
    const int n1 = 4194304 / 4;   // x chunks
    const int n2 = 3145728 / 4;   // w_qkv chunks
    int i = blockIdx.x * 256 + threadIdx.x;
    const int stride = gridDim.x * 256;
    for (; i < n1 + n2; i += stride) {
        float4 v;
        ushort4* dst;
        if (i < n1) { v = ((const float4*)X)[i];       dst = (ushort4*)Xb + i; }
        else        { v = ((const float4*)Wq)[i - n1]; dst = (ushort4*)Wqb + (i - n1); }
        ushort4 o;
        o.x = f2bf(v.x); o.y = f2bf(v.y); o.z = f2bf(v.z); o.w = f2bf(v.w);
        *dst = o;
    }
}

__global__ __launch_bounds__(256, 2)
void cvt_w_kernel(const float* __restrict__ W, u16* __restrict__ Wb)
{
    int i = blockIdx.x * 256 + threadIdx.x;     // 262144 chunks, grid covers exactly
    float4 v = ((const float4*)W)[i];
    ushort4 o;
    o.x = f2bf(v.x); o.y = f2bf(v.y); o.z = f2bf(v.z); o.w = f2bf(v.w);
    ((ushort4*)Wb)[i] = o;
}

// ---------------------------------------------------------------------------
// Kernel 1: qkv = x @ w_qkv^T (M=4096,N=3072,K=1024), bf16 in, RoPE epilogue.
// m97 pattern: global_load_lds 16B staging into unpadded XOR-swizzled LDS.
// ---------------------------------------------------------------------------
__global__ __launch_bounds__(256, 2)
void qkv_rope_kernel(const u16* __restrict__ X, const u16* __restrict__ W,
                     const float* __restrict__ Cos, const float* __restrict__ Sin,
                     u16* __restrict__ Qo, u16* __restrict__ Ko, u16* __restrict__ Vo)
{
    __shared__ __align__(16) u16 As[128 * 64];
    __shared__ __align__(16) u16 Bs[128 * 64];
    const int tid  = threadIdx.x;
    const int lane = tid & 63, wave = tid >> 6;
    const int l15  = lane & 15, q4 = lane >> 4;
    const int wm = (wave >> 1) * 64, wn = (wave & 1) * 64;
    const int m0 = blockIdx.y * 128, n0 = blockIdx.x * 128;
    const int srow = lane >> 3;
    const int scol = ((lane & 7) ^ srow) * 8;

    f32x4 acc[4][4];
    #pragma unroll
    for (int i = 0; i < 4; i++)
        #pragma unroll
        for (int j = 0; j < 4; j++) { f32x4 z = {}; acc[i][j] = z; }

    for (int k0 = 0; k0 < 1024; k0 += 64) {
        __syncthreads();
        #pragma unroll
        for (int i = 0; i < 4; i++) {
            int rb = wave * 32 + i * 8;
            gl_lds16(X + (size_t)(m0 + rb + srow) * 1024 + k0 + scol, As + rb * 64);
            gl_lds16(W + (size_t)(n0 + rb + srow) * 1024 + k0 + scol, Bs + rb * 64);
        }
        __syncthreads();
        #pragma unroll
        for (int ks = 0; ks < 2; ks++) {
            const int ch = (((4 * ks + q4) ^ (l15 & 7)) * 8);
            bf16x8 af[4], bfr[4];
            #pragma unroll
            for (int i = 0; i < 4; i++) {
                af[i]  = *(const bf16x8*)&As[(wm + i * 16 + l15) * 64 + ch];
                bfr[i] = *(const bf16x8*)&Bs[(wn + i * 16 + l15) * 64 + ch];
            }
            #pragma unroll
            for (int mi = 0; mi < 4; mi++)
                #pragma unroll
                for (int ni = 0; ni < 4; ni++)
                    acc[mi][ni] = __builtin_amdgcn_mfma_f32_16x16x32_bf16(
                        af[mi], bfr[ni], acc[mi][ni], 0, 0, 0);
        }
    }

    #pragma unroll
    for (int mi = 0; mi < 4; mi++) {
        #pragma unroll
        for (int r = 0; r < 4; r++) {
            int row = m0 + wm + mi * 16 + q4 * 4 + r;     // global m = b*T + t
            int b = row >> 11, t = row & 2047;
            #pragma unroll
            for (int ni = 0; ni < 4; ni++) {
                int col = n0 + wn + ni * 16 + l15;        // global f in [0,3072)
                float v = acc[mi][ni][r];
                int sec = col >> 10;                      // 0=q 1=k 2=v
                int hh  = (col >> 6) & 15;
                int d   = col & 63;
                if (sec < 2) {
                    float cs = Cos[t * 64 + d];
                    float sn = Sin[t * 64 + d];
                    float partner = acc[mi][ni ^ 2][r];   // col ^ 32, same lane
                    float rot = (d < 32) ? -partner : partner;
                    v = v * cs + rot * sn;
                    u16* dst = (sec == 0) ? Qo : Ko;
                    dst[(((size_t)(b * 16 + hh)) * 2048 + t) * 64 + d] = f2bf(v);
                } else {
                    Vo[(((size_t)(b * 16 + hh)) * 64 + d) * 2048 + t] = f2bf(v);  // [b,h,d,t]
                }
            }
        }
    }
}

// ---------------------------------------------------------------------------
// Kernel 2: causal flash attention. 64 q-rows/block, 4 waves x 16 rows each.
// Grid = 1024 blocks (32 q-tiles x 32 bh), LPT order; 4 blocks/CU = 16
// waves/CU. K/V staged via global_load_lds into swizzled LDS (4 issues/wave).
// Ps is wave-private (no barrier needed: per-lane may-alias ordering + LDS
// in-order per wave). Mask only on the diagonal tile.
// ---------------------------------------------------------------------------
__global__ __launch_bounds__(256, 4)
void attn_kernel(const u16* __restrict__ Q, const u16* __restrict__ Kg,
                 const u16* __restrict__ Vt, u16* __restrict__ Oh)
{
    __shared__ __align__(16) u16 Ks[64 * 64];
    __shared__ __align__(16) u16 Vs[64 * 64];
    __shared__ __align__(16) __bf16 Ps[4][16][72];

    const int bx = blockIdx.x;
    const int qt = 31 - (bx >> 5);     // longest blocks launch first
    const int bh = bx & 31;
    const int b = bh >> 4, h = bh & 15;
    const int tid = threadIdx.x, wave = tid >> 6, lane = tid & 63;
    const int l15 = lane & 15, q4 = lane >> 4;
    const int srow = lane >> 3;
    const int scol = ((lane & 7) ^ srow) * 8;

    const size_t head_off = (size_t)bh * 2048 * 64;
    const u16* Qb = Q  + head_off;
    const u16* Kb = Kg + head_off;
    const u16* Vb = Vt + head_off;     // [d][t] per head

    const int qrow0 = qt * 64 + wave * 16;   // this wave's 16 q-rows

    // Q fragments: A[m=l15][k=q4*8+j+32*ks]
    bf16x8 qf[2];
    #pragma unroll
    for (int ks = 0; ks < 2; ks++)
        qf[ks] = *(const bf16x8*)(Qb + (size_t)(qrow0 + l15) * 64 + ks * 32 + q4 * 8);

    f32x4 o[4];
    float mst[4], lst[4];
    #pragma unroll
    for (int ni = 0; ni < 4; ni++) { f32x4 z = {}; o[ni] = z; }
    #pragma unroll
    for (int r = 0; r < 4; r++) { mst[r] = -1e30f; lst[r] = 0.f; }

    const int nkv = qt + 1;            // 64-wide kv tiles (block-uniform)
    for (int it = 0; it < nkv; it++) {
        const int k0 = it * 64;
        __syncthreads();               // protect Ks/Vs from prev iteration reads
        #pragma unroll
        for (int i = 0; i < 4; i++) {  // 16 row-block issues: 8 K + 8 V
            int id = wave * 4 + i;
            if (id < 8)
                gl_lds16(Kb + (size_t)(k0 + id * 8 + srow) * 64 + scol, Ks + id * 8 * 64);
            else
                gl_lds16(Vb + (size_t)((id - 8) * 8 + srow) * 2048 + k0 + scol,
                         Vs + (id - 8) * 8 * 64);
        }
        __syncthreads();

        // S = Q K^T
        f32x4 s[4];
        #pragma unroll
        for (int ni = 0; ni < 4; ni++) { f32x4 z = {}; s[ni] = z; }
        #pragma unroll
        for (int ks = 0; ks < 2; ks++) {
            const int ch = (((4 * ks + q4) ^ (l15 & 7)) * 8);
            bf16x8 kf[4];
            #pragma unroll
            for (int ni = 0; ni < 4; ni++)
                kf[ni] = *(const bf16x8*)&Ks[(ni * 16 + l15) * 64 + ch];
            #pragma unroll
            for (int ni = 0; ni < 4; ni++)
                s[ni] = __builtin_amdgcn_mfma_f32_16x16x32_bf16(qf[ks], kf[ni], s[ni], 0, 0, 0);
        }

        const bool diag = (it == qt);

        // scale + (diag) mask + online softmax; rows on (q4,r), cols on (ni,l15)
        #pragma unroll
        for (int r = 0; r < 4; r++) {
            const int tq = qrow0 + q4 * 4 + r;
            float rm = -1e30f;
            #pragma unroll
            for (int ni = 0; ni < 4; ni++) {
                float sv = s[ni][r] * 0.125f;
                if (diag && (k0 + ni * 16 + l15 > tq)) sv = -1e30f;
                s[ni][r] = sv;
                rm = fmaxf(rm, sv);
            }
            #pragma unroll
            for (int off = 1; off < 16; off <<= 1)
                rm = fmaxf(rm, __shfl_xor(rm, off, 64));
            float mnew  = fmaxf(mst[r], rm);
            float alpha = __expf(mst[r] - mnew);
            float rs = 0.f;
            #pragma unroll
            for (int ni = 0; ni < 4; ni++) {
                float p = __expf(s[ni][r] - mnew);
                s[ni][r] = p;
                rs += p;
            }
            #pragma unroll
            for (int off = 1; off < 16; off <<= 1)
                rs += __shfl_xor(rs, off, 64);
            lst[r] = lst[r] * alpha + rs;
            mst[r] = mnew;
            #pragma unroll
            for (int ni = 0; ni < 4; ni++)
                o[ni][r] *= alpha;
            #pragma unroll
            for (int ni = 0; ni < 4; ni++)
                Ps[wave][q4 * 4 + r][ni * 16 + l15] = (__bf16)s[ni][r];
        }

        // O += P V (Ps wave-private; in-wave LDS ordering suffices)
        #pragma unroll
        for (int ks = 0; ks < 2; ks++) {
            const int ch = (((4 * ks + q4) ^ (l15 & 7)) * 8);
            bf16x8 pa = *(const bf16x8*)&Ps[wave][l15][ks * 32 + q4 * 8];
            bf16x8 vf[4];
            #pragma unroll
            for (int ni = 0; ni < 4; ni++)
                vf[ni] = *(const bf16x8*)&Vs[(ni * 16 + l15) * 64 + ch];
            #pragma unroll
            for (int ni = 0; ni < 4; ni++)
                o[ni] = __builtin_amdgcn_mfma_f32_16x16x32_bf16(pa, vf[ni], o[ni], 0, 0, 0);
        }
    }

    // Epilogue: O / l -> Oh[b,t,h,d] (= [4096,1024] rows)
    #pragma unroll
    for (int r = 0; r < 4; r++) {
        int t = qrow0 + q4 * 4 + r;
        float inv = 1.0f / lst[r];
        #pragma unroll
        for (int ni = 0; ni < 4; ni++) {
            int d = ni * 16 + l15;
            Oh[(((size_t)(b * 2048 + t)) * 16 + h) * 64 + d] = f2bf(o[ni][r] * inv);
        }
    }
}

// ---------------------------------------------------------------------------
// Kernel 3: out = Oh @ w_out^T (M=4096,N=1024,K=1024), fp32 out.
// 128x64 tiles -> 512 blocks (2/CU).
// ---------------------------------------------------------------------------
__global__ __launch_bounds__(256, 2)
void outproj_kernel(const u16* __restrict__ A, const u16* __restrict__ W,
                    float* __restrict__ Cout)
{
    __shared__ __align__(16) u16 As[128 * 64];
    __shared__ __align__(16) u16 Bs[64 * 64];
    const int tid  = threadIdx.x;
    const int lane = tid & 63, wave = tid >> 6;
    const int l15  = lane & 15, q4 = lane >> 4;
    const int wm = (wave >> 1) * 64, wn = (wave & 1) * 32;
    const int m0 = blockIdx.y * 128, n0 = blockIdx.x * 64;
    const int srow = lane >> 3;
    const int scol = ((lane & 7) ^ srow) * 8;

    f32x4 acc[4][2];
    #pragma unroll
    for (int i = 0; i < 4; i++)
        #pragma unroll
        for (int j = 0; j < 2; j++) { f32x4 z = {}; acc[i][j] = z; }

    for (int k0 = 0; k0 < 1024; k0 += 64) {
        __syncthreads();
        #pragma unroll
        for (int i = 0; i < 6; i++) {           // 24 issues: 16 A + 8 B
            int id = wave * 6 + i;
            if (id < 16) {
                int rb = id * 8;
                gl_lds16(A + (size_t)(m0 + rb + srow) * 1024 + k0 + scol, As + rb * 64);
            } else {
                int rb = (id - 16) * 8;
                gl_lds16(W + (size_t)(n0 + rb + srow) * 1024 + k0 + scol, Bs + rb * 64);
            }
        }
        __syncthreads();
        #pragma unroll
        for (int ks = 0; ks < 2; ks++) {
            const int ch = (((4 * ks + q4) ^ (l15 & 7)) * 8);
            bf16x8 af[4], bfr[2];
            #pragma unroll
            for (int i = 0; i < 4; i++)
                af[i] = *(const bf16x8*)&As[(wm + i * 16 + l15) * 64 + ch];
            #pragma unroll
            for (int ni = 0; ni < 2; ni++)
                bfr[ni] = *(const bf16x8*)&Bs[(wn + ni * 16 + l15) * 64 + ch];
            #pragma unroll
            for (int mi = 0; mi < 4; mi++)
                #pragma unroll
                for (int ni = 0; ni < 2; ni++)
                    acc[mi][ni] = __builtin_amdgcn_mfma_f32_16x16x32_bf16(
                        af[mi], bfr[ni], acc[mi][ni], 0, 0, 0);
        }
    }

    #pragma unroll
    for (int mi = 0; mi < 4; mi++)
        #pragma unroll
        for (int r = 0; r < 4; r++) {
            int row = m0 + wm + mi * 16 + q4 * 4 + r;
            #pragma unroll
            for (int ni = 0; ni < 2; ni++) {
                int col = n0 + wn + ni * 16 + l15;
                Cout[(size_t)row * 1024 + col] = acc[mi][ni][r];
            }
        }
}

extern "C" void kernel_launch(void* const* d_in, const int* in_sizes, int n_in,
                              void* d_out, int out_size, void* d_ws, size_t ws_size,
                              hipStream_t stream) {
    (void)in_sizes; (void)n_in; (void)out_size; (void)ws_size;
    const float* x     = (const float*)d_in[0];   // [2,2048,1024] fp32
    const float* cosp  = (const float*)d_in[1];   // [2048,64] fp32
    const float* sinp  = (const float*)d_in[2];   // [2048,64] fp32
    const float* w_qkv = (const float*)d_in[3];   // [3072,1024] fp32
    const float* w_out = (const float*)d_in[4];   // [1024,1024] fp32
    float* out = (float*)d_out;                   // [2,2048,1024] fp32

    const size_t NELEM = (size_t)2 * 2048 * 1024;  // 4,194,304
    // d_out (16.8 MB fp32): Q bf16 in lower half, X bf16 in upper half.
    // Both dead before outproj overwrites all of d_out.
    u16* Q   = (u16*)d_out;            // [b,h,t,d]
    u16* Xb  = (u16*)d_out + NELEM;    // [4096,1024] bf16
    // ws (25.2 MB):
    u16* K   = (u16*)d_ws;             // [b,h,t,d]
    u16* Vt  = K + NELEM;              // [b,h,d,t]
    u16* Oh  = Vt + NELEM;             // [b,t,h,d]
    u16* Wqb = Oh;                     // w_qkv bf16 — dead before attn writes Oh
    u16* Wob = K;                      // w_out bf16 — written after attn (K dead)

    cvt_xw_kernel<<<7168, 256, 0, stream>>>(x, w_qkv, Xb, Wqb);
    qkv_rope_kernel<<<dim3(24, 32), 256, 0, stream>>>(Xb, Wqb, cosp, sinp, Q, K, Vt);
    attn_kernel<<<1024, 256, 0, stream>>>(Q, K, Vt, Oh);
    cvt_w_kernel<<<1024, 256, 0, stream>>>(w_out, Wob);
    outproj_kernel<<<dim3(16, 32), 256, 0, stream>>>(Oh, Wob, out);
}

// Round 7
// 199.530 us; speedup vs baseline: 1.8239x; 1.1042x over previous
//
#include <hip/hip_runtime.h>

typedef unsigned short u16;
typedef __bf16 bf16x8 __attribute__((ext_vector_type(8)));
typedef __bf16 bf16x4 __attribute__((ext_vector_type(4)));
typedef float f32x4 __attribute__((ext_vector_type(4)));

__device__ __forceinline__ u16 f2bf(float f) {
    union { float f; unsigned int i; } v; v.f = f;
    unsigned int x = v.i;
    x += 0x7fffu + ((x >> 16) & 1u);   // round-to-nearest-even
    return (u16)(x >> 16);
}

// Async global->LDS 16B copy. LDS dest is wave-uniform base + lane*16.
__device__ __forceinline__ void gl_lds16(const u16* g, u16* l) {
    __builtin_amdgcn_global_load_lds(
        (const __attribute__((address_space(1))) void*)g,
        (__attribute__((address_space(3))) void*)l, 16, 0, 0);
}

// ---------------------------------------------------------------------------
// cvt: fp32 -> bf16, vectorized.
// ---------------------------------------------------------------------------
__global__ __launch_bounds__(256, 2)
void cvt_xw_kernel(const float* __restrict__ X, const float* __restrict__ Wq,
                   u16* __restrict__ Xb, u16* __restrict__ Wqb)
{
    const int n1 = 4194304 / 4;   // x chunks
    const int n2 = 3145728 / 4;   // w_qkv chunks
    int i = blockIdx.x * 256 + threadIdx.x;
    const int stride = gridDim.x * 256;
    for (; i < n1 + n2; i += stride) {
        float4 v;
        ushort4* dst;
        if (i < n1) { v = ((const float4*)X)[i];       dst = (ushort4*)Xb + i; }
        else        { v = ((const float4*)Wq)[i - n1]; dst = (ushort4*)Wqb + (i - n1); }
        ushort4 o;
        o.x = f2bf(v.x); o.y = f2bf(v.y); o.z = f2bf(v.z); o.w = f2bf(v.w);
        *dst = o;
    }
}

__global__ __launch_bounds__(256, 2)
void cvt_w_kernel(const float* __restrict__ W, u16* __restrict__ Wb)
{
    int i = blockIdx.x * 256 + threadIdx.x;     // 262144 chunks, grid covers exactly
    float4 v = ((const float4*)W)[i];
    ushort4 o;
    o.x = f2bf(v.x); o.y = f2bf(v.y); o.z = f2bf(v.z); o.w = f2bf(v.w);
    ((ushort4*)Wb)[i] = o;
}

// ---------------------------------------------------------------------------
// Kernel 1: qkv = x @ w_qkv^T (M=4096,N=3072,K=1024), bf16 in, RoPE epilogue.
// m97 pattern: global_load_lds 16B staging into unpadded XOR-swizzled LDS.
// ---------------------------------------------------------------------------
__global__ __launch_bounds__(256, 2)
void qkv_rope_kernel(const u16* __restrict__ X, const u16* __restrict__ W,
                     const float* __restrict__ Cos, const float* __restrict__ Sin,
                     u16* __restrict__ Qo, u16* __restrict__ Ko, u16* __restrict__ Vo)
{
    __shared__ __align__(16) u16 As[128 * 64];
    __shared__ __align__(16) u16 Bs[128 * 64];
    const int tid  = threadIdx.x;
    const int lane = tid & 63, wave = tid >> 6;
    const int l15  = lane & 15, q4 = lane >> 4;
    const int wm = (wave >> 1) * 64, wn = (wave & 1) * 64;
    const int m0 = blockIdx.y * 128, n0 = blockIdx.x * 128;
    const int srow = lane >> 3;
    const int scol = ((lane & 7) ^ srow) * 8;

    f32x4 acc[4][4];
    #pragma unroll
    for (int i = 0; i < 4; i++)
        #pragma unroll
        for (int j = 0; j < 4; j++) { f32x4 z = {}; acc[i][j] = z; }

    for (int k0 = 0; k0 < 1024; k0 += 64) {
        __syncthreads();
        #pragma unroll
        for (int i = 0; i < 4; i++) {
            int rb = wave * 32 + i * 8;
            gl_lds16(X + (size_t)(m0 + rb + srow) * 1024 + k0 + scol, As + rb * 64);
            gl_lds16(W + (size_t)(n0 + rb + srow) * 1024 + k0 + scol, Bs + rb * 64);
        }
        __syncthreads();
        #pragma unroll
        for (int ks = 0; ks < 2; ks++) {
            const int ch = (((4 * ks + q4) ^ (l15 & 7)) * 8);
            bf16x8 af[4], bfr[4];
            #pragma unroll
            for (int i = 0; i < 4; i++) {
                af[i]  = *(const bf16x8*)&As[(wm + i * 16 + l15) * 64 + ch];
                bfr[i] = *(const bf16x8*)&Bs[(wn + i * 16 + l15) * 64 + ch];
            }
            #pragma unroll
            for (int mi = 0; mi < 4; mi++)
                #pragma unroll
                for (int ni = 0; ni < 4; ni++)
                    acc[mi][ni] = __builtin_amdgcn_mfma_f32_16x16x32_bf16(
                        af[mi], bfr[ni], acc[mi][ni], 0, 0, 0);
        }
    }

    #pragma unroll
    for (int mi = 0; mi < 4; mi++) {
        #pragma unroll
        for (int r = 0; r < 4; r++) {
            int row = m0 + wm + mi * 16 + q4 * 4 + r;     // global m = b*T + t
            int b = row >> 11, t = row & 2047;
            #pragma unroll
            for (int ni = 0; ni < 4; ni++) {
                int col = n0 + wn + ni * 16 + l15;        // global f in [0,3072)
                float v = acc[mi][ni][r];
                int sec = col >> 10;                      // 0=q 1=k 2=v
                int hh  = (col >> 6) & 15;
                int d   = col & 63;
                if (sec < 2) {
                    float cs = Cos[t * 64 + d];
                    float sn = Sin[t * 64 + d];
                    float partner = acc[mi][ni ^ 2][r];   // col ^ 32, same lane
                    float rot = (d < 32) ? -partner : partner;
                    v = v * cs + rot * sn;
                    u16* dst = (sec == 0) ? Qo : Ko;
                    dst[(((size_t)(b * 16 + hh)) * 2048 + t) * 64 + d] = f2bf(v);
                } else {
                    Vo[(((size_t)(b * 16 + hh)) * 64 + d) * 2048 + t] = f2bf(v);  // [b,h,d,t]
                }
            }
        }
    }
}

// ---------------------------------------------------------------------------
// Kernel 2: causal flash attention. 64 q-rows/block, 4 waves x 16 rows each.
// S^T formulation: S^T = K·Q^T so each lane owns ONE q-row (q = l15);
// row-max = in-reg tree over 16 + 2 shuffles (xor16, xor32). Row-sum l is
// accumulated by an extra ones-column MFMA in the PV phase (no shuffles).
// alpha moves to row orientation via 4 flat shuffles. Q pre-scaled by 0.125.
// ---------------------------------------------------------------------------
__global__ __launch_bounds__(256, 4)
void attn_kernel(const u16* __restrict__ Q, const u16* __restrict__ Kg,
                 const u16* __restrict__ Vt, u16* __restrict__ Oh)
{
    __shared__ __align__(16) u16 Ks[64 * 64];
    __shared__ __align__(16) u16 Vs[64 * 64];
    __shared__ __align__(16) __bf16 Ps[4][16][72];

    const int bx = blockIdx.x;
    const int qt = 31 - (bx >> 5);     // longest blocks launch first (LPT)
    const int bh = bx & 31;
    const int b = bh >> 4, h = bh & 15;
    const int tid = threadIdx.x, wave = tid >> 6, lane = tid & 63;
    const int l15 = lane & 15, q4 = lane >> 4;
    const int srow = lane >> 3;
    const int scol = ((lane & 7) ^ srow) * 8;

    const size_t head_off = (size_t)bh * 2048 * 64;
    const u16* Qb = Q  + head_off;
    const u16* Kb = Kg + head_off;
    const u16* Vb = Vt + head_off;     // [d][t] per head

    const int qrow0 = qt * 64 + wave * 16;   // this wave's 16 q-rows

    // Q fragments (used as B operand): B[n=l15][k=q4*8+j+32*ks], pre-scaled
    // by 1/8 (exact in bf16: exponent shift).
    bf16x8 qf[2];
    #pragma unroll
    for (int ks = 0; ks < 2; ks++) {
        bf16x8 t = *(const bf16x8*)(Qb + (size_t)(qrow0 + l15) * 64 + ks * 32 + q4 * 8);
        #pragma unroll
        for (int j = 0; j < 8; j++) t[j] = (__bf16)((float)t[j] * 0.125f);
        qf[ks] = t;
    }

    // ones B-fragment for the l-accumulator MFMA
    bf16x8 ones;
    #pragma unroll
    for (int j = 0; j < 8; j++) ones[j] = (__bf16)1.0f;

    f32x4 o[4];                       // O rows q=q4*4+r(+qrow0), cols d=ni*16+l15
    f32x4 ol = {};                    // row-sum accumulator (same orientation)
    float mstq = -1e30f;              // running max for THIS lane's q (=l15)
    #pragma unroll
    for (int ni = 0; ni < 4; ni++) { f32x4 z = {}; o[ni] = z; }

    const int nkv = qt + 1;            // 64-wide kv tiles (block-uniform)
    for (int it = 0; it < nkv; it++) {
        const int k0 = it * 64;
        __syncthreads();               // protect Ks/Vs from prev iteration reads
        #pragma unroll
        for (int i = 0; i < 4; i++) {  // 16 row-block issues: 8 K + 8 V
            int id = wave * 4 + i;
            if (id < 8)
                gl_lds16(Kb + (size_t)(k0 + id * 8 + srow) * 64 + scol, Ks + id * 8 * 64);
            else
                gl_lds16(Vb + (size_t)((id - 8) * 8 + srow) * 2048 + k0 + scol,
                         Vs + (id - 8) * 8 * 64);
        }
        __syncthreads();

        // S^T = K Q^T : A = kf[mi] (kv rows), B = qf (q cols).
        // st[mi][r]: kv = mi*16 + q4*4 + r, q = l15.
        f32x4 st[4];
        #pragma unroll
        for (int mi = 0; mi < 4; mi++) { f32x4 z = {}; st[mi] = z; }
        #pragma unroll
        for (int ks = 0; ks < 2; ks++) {
            const int ch = (((4 * ks + q4) ^ (l15 & 7)) * 8);
            bf16x8 kf[4];
            #pragma unroll
            for (int mi = 0; mi < 4; mi++)
                kf[mi] = *(const bf16x8*)&Ks[(mi * 16 + l15) * 64 + ch];
            #pragma unroll
            for (int mi = 0; mi < 4; mi++)
                st[mi] = __builtin_amdgcn_mfma_f32_16x16x32_bf16(kf[mi], qf[ks], st[mi], 0, 0, 0);
        }

        // mask (diag tile only) + row max: in-reg tree + 2 shuffle stages
        float rm = -1e30f;
        if (it == qt) {
            const int tq = qrow0 + l15;
            #pragma unroll
            for (int mi = 0; mi < 4; mi++)
                #pragma unroll
                for (int r = 0; r < 4; r++) {
                    float v = st[mi][r];
                    if (k0 + mi * 16 + q4 * 4 + r > tq) v = -1e30f;
                    st[mi][r] = v;
                    rm = fmaxf(rm, v);
                }
        } else {
            #pragma unroll
            for (int mi = 0; mi < 4; mi++)
                #pragma unroll
                for (int r = 0; r < 4; r++)
                    rm = fmaxf(rm, st[mi][r]);
        }
        rm = fmaxf(rm, __shfl_xor(rm, 16, 64));
        rm = fmaxf(rm, __shfl_xor(rm, 32, 64));

        float mnew  = fmaxf(mstq, rm);
        float alpha = __expf(mstq - mnew);
        mstq = mnew;

        // exp + write P^T to Ps in A-layout rows (q = l15): 8B stores
        #pragma unroll
        for (int mi = 0; mi < 4; mi++) {
            bf16x4 p4;
            #pragma unroll
            for (int r = 0; r < 4; r++)
                p4[r] = (__bf16)__expf(st[mi][r] - mnew);
            *(bf16x4*)&Ps[wave][l15][mi * 16 + q4 * 4] = p4;
        }

        // alpha for row orientation (q = qrow0 + q4*4 + r): flat shuffles
        float ar[4];
        #pragma unroll
        for (int r = 0; r < 4; r++)
            ar[r] = __shfl(alpha, q4 * 4 + r, 64);
        #pragma unroll
        for (int ni = 0; ni < 4; ni++)
            #pragma unroll
            for (int r = 0; r < 4; r++)
                o[ni][r] *= ar[r];
        #pragma unroll
        for (int r = 0; r < 4; r++)
            ol[r] *= ar[r];

        // O += P V ; l += P·1   (Ps wave-private; in-wave LDS ordering)
        #pragma unroll
        for (int ks = 0; ks < 2; ks++) {
            const int ch = (((4 * ks + q4) ^ (l15 & 7)) * 8);
            bf16x8 pa = *(const bf16x8*)&Ps[wave][l15][ks * 32 + q4 * 8];
            bf16x8 vf[4];
            #pragma unroll
            for (int ni = 0; ni < 4; ni++)
                vf[ni] = *(const bf16x8*)&Vs[(ni * 16 + l15) * 64 + ch];
            #pragma unroll
            for (int ni = 0; ni < 4; ni++)
                o[ni] = __builtin_amdgcn_mfma_f32_16x16x32_bf16(pa, vf[ni], o[ni], 0, 0, 0);
            ol = __builtin_amdgcn_mfma_f32_16x16x32_bf16(pa, ones, ol, 0, 0, 0);
        }
    }

    // Epilogue: O / l -> Oh[b,t,h,d] (= [4096,1024] rows)
    #pragma unroll
    for (int r = 0; r < 4; r++) {
        int t = qrow0 + q4 * 4 + r;
        float inv = 1.0f / ol[r];
        #pragma unroll
        for (int ni = 0; ni < 4; ni++) {
            int d = ni * 16 + l15;
            Oh[(((size_t)(b * 2048 + t)) * 16 + h) * 64 + d] = f2bf(o[ni][r] * inv);
        }
    }
}

// ---------------------------------------------------------------------------
// Kernel 3: out = Oh @ w_out^T (M=4096,N=1024,K=1024), fp32 out.
// 128x64 tiles -> 512 blocks (2/CU).
// ---------------------------------------------------------------------------
__global__ __launch_bounds__(256, 2)
void outproj_kernel(const u16* __restrict__ A, const u16* __restrict__ W,
                    float* __restrict__ Cout)
{
    __shared__ __align__(16) u16 As[128 * 64];
    __shared__ __align__(16) u16 Bs[64 * 64];
    const int tid  = threadIdx.x;
    const int lane = tid & 63, wave = tid >> 6;
    const int l15  = lane & 15, q4 = lane >> 4;
    const int wm = (wave >> 1) * 64, wn = (wave & 1) * 32;
    const int m0 = blockIdx.y * 128, n0 = blockIdx.x * 64;
    const int srow = lane >> 3;
    const int scol = ((lane & 7) ^ srow) * 8;

    f32x4 acc[4][2];
    #pragma unroll
    for (int i = 0; i < 4; i++)
        #pragma unroll
        for (int j = 0; j < 2; j++) { f32x4 z = {}; acc[i][j] = z; }

    for (int k0 = 0; k0 < 1024; k0 += 64) {
        __syncthreads();
        #pragma unroll
        for (int i = 0; i < 6; i++) {           // 24 issues: 16 A + 8 B
            int id = wave * 6 + i;
            if (id < 16) {
                int rb = id * 8;
                gl_lds16(A + (size_t)(m0 + rb + srow) * 1024 + k0 + scol, As + rb * 64);
            } else {
                int rb = (id - 16) * 8;
                gl_lds16(W + (size_t)(n0 + rb + srow) * 1024 + k0 + scol, Bs + rb * 64);
            }
        }
        __syncthreads();
        #pragma unroll
        for (int ks = 0; ks < 2; ks++) {
            const int ch = (((4 * ks + q4) ^ (l15 & 7)) * 8);
            bf16x8 af[4], bfr[2];
            #pragma unroll
            for (int i = 0; i < 4; i++)
                af[i] = *(const bf16x8*)&As[(wm + i * 16 + l15) * 64 + ch];
            #pragma unroll
            for (int ni = 0; ni < 2; ni++)
                bfr[ni] = *(const bf16x8*)&Bs[(wn + ni * 16 + l15) * 64 + ch];
            #pragma unroll
            for (int mi = 0; mi < 4; mi++)
                #pragma unroll
                for (int ni = 0; ni < 2; ni++)
                    acc[mi][ni] = __builtin_amdgcn_mfma_f32_16x16x32_bf16(
                        af[mi], bfr[ni], acc[mi][ni], 0, 0, 0);
        }
    }

    #pragma unroll
    for (int mi = 0; mi < 4; mi++)
        #pragma unroll
        for (int r = 0; r < 4; r++) {
            int row = m0 + wm + mi * 16 + q4 * 4 + r;
            #pragma unroll
            for (int ni = 0; ni < 2; ni++) {
                int col = n0 + wn + ni * 16 + l15;
                Cout[(size_t)row * 1024 + col] = acc[mi][ni][r];
            }
        }
}

extern "C" void kernel_launch(void* const* d_in, const int* in_sizes, int n_in,
                              void* d_out, int out_size, void* d_ws, size_t ws_size,
                              hipStream_t stream) {
    (void)in_sizes; (void)n_in; (void)out_size; (void)ws_size;
    const float* x     = (const float*)d_in[0];   // [2,2048,1024] fp32
    const float* cosp  = (const float*)d_in[1];   // [2048,64] fp32
    const float* sinp  = (const float*)d_in[2];   // [2048,64] fp32
    const float* w_qkv = (const float*)d_in[3];   // [3072,1024] fp32
    const float* w_out = (const float*)d_in[4];   // [1024,1024] fp32
    float* out = (float*)d_out;                   // [2,2048,1024] fp32

    const size_t NELEM = (size_t)2 * 2048 * 1024;  // 4,194,304
    // d_out (16.8 MB fp32): Q bf16 in lower half, X bf16 in upper half.
    // Both dead before outproj overwrites all of d_out.
    u16* Q   = (u16*)d_out;            // [b,h,t,d]
    u16* Xb  = (u16*)d_out + NELEM;    // [4096,1024] bf16
    // ws (25.2 MB):
    u16* K   = (u16*)d_ws;             // [b,h,t,d]
    u16* Vt  = K + NELEM;              // [b,h,d,t]
    u16* Oh  = Vt + NELEM;             // [b,t,h,d]
    u16* Wqb = Oh;                     // w_qkv bf16 — dead before attn writes Oh
    u16* Wob = K;                      // w_out bf16 — written after attn (K dead)

    cvt_xw_kernel<<<7168, 256, 0, stream>>>(x, w_qkv, Xb, Wqb);
    qkv_rope_kernel<<<dim3(24, 32), 256, 0, stream>>>(Xb, Wqb, cosp, sinp, Q, K, Vt);
    attn_kernel<<<1024, 256, 0, stream>>>(Q, K, Vt, Oh);
    cvt_w_kernel<<<1024, 256, 0, stream>>>(w_out, Wob);
    outproj_kernel<<<dim3(16, 32), 256, 0, stream>>>(Oh, Wob, out);
}

// Round 8
// 190.411 us; speedup vs baseline: 1.9113x; 1.0479x over previous
//
#include <hip/hip_runtime.h>

typedef unsigned short u16;
typedef __bf16 bf16x8 __attribute__((ext_vector_type(8)));
typedef __bf16 bf16x4 __attribute__((ext_vector_type(4)));
typedef float f32x4 __attribute__((ext_vector_type(4)));

__device__ __forceinline__ u16 f2bf(float f) {
    union { float f; unsigned int i; } v; v.f = f;
    unsigned int x = v.i;
    x += 0x7fffu + ((x >> 16) & 1u);   // round-to-nearest-even
    return (u16)(x >> 16);
}

// Async global->LDS 16B copy. LDS dest is wave-uniform base + lane*16.
__device__ __forceinline__ void gl_lds16(const u16* g, u16* l) {
    __builtin_amdgcn_global_load_lds(
        (const __attribute__((address_space(1))) void*)g,
        (__attribute__((address_space(3))) void*)l, 16, 0, 0);
}

// ---------------------------------------------------------------------------
// cvt: fp32 -> bf16, vectorized.
// ---------------------------------------------------------------------------
__global__ __launch_bounds__(256, 2)
void cvt_xw_kernel(const float* __restrict__ X, const float* __restrict__ Wq,
                   u16* __restrict__ Xb, u16* __restrict__ Wqb)
{
    const int n1 = 4194304 / 4;   // x chunks
    const int n2 = 3145728 / 4;   // w_qkv chunks
    int i = blockIdx.x * 256 + threadIdx.x;
    const int stride = gridDim.x * 256;
    for (; i < n1 + n2; i += stride) {
        float4 v;
        ushort4* dst;
        if (i < n1) { v = ((const float4*)X)[i];       dst = (ushort4*)Xb + i; }
        else        { v = ((const float4*)Wq)[i - n1]; dst = (ushort4*)Wqb + (i - n1); }
        ushort4 o;
        o.x = f2bf(v.x); o.y = f2bf(v.y); o.z = f2bf(v.z); o.w = f2bf(v.w);
        *dst = o;
    }
}

__global__ __launch_bounds__(256, 2)
void cvt_w_kernel(const float* __restrict__ W, u16* __restrict__ Wb)
{
    int i = blockIdx.x * 256 + threadIdx.x;     // 262144 chunks, grid covers exactly
    float4 v = ((const float4*)W)[i];
    ushort4 o;
    o.x = f2bf(v.x); o.y = f2bf(v.y); o.z = f2bf(v.z); o.w = f2bf(v.w);
    ((ushort4*)Wb)[i] = o;
}

// ---------------------------------------------------------------------------
// Kernel 1: qkv = x @ w_qkv^T (M=4096,N=3072,K=1024), bf16 in, RoPE epilogue.
// m97 pattern: global_load_lds 16B staging into unpadded XOR-swizzled LDS.
// ---------------------------------------------------------------------------
__global__ __launch_bounds__(256, 2)
void qkv_rope_kernel(const u16* __restrict__ X, const u16* __restrict__ W,
                     const float* __restrict__ Cos, const float* __restrict__ Sin,
                     u16* __restrict__ Qo, u16* __restrict__ Ko, u16* __restrict__ Vo)
{
    __shared__ __align__(16) u16 As[128 * 64];
    __shared__ __align__(16) u16 Bs[128 * 64];
    const int tid  = threadIdx.x;
    const int lane = tid & 63, wave = tid >> 6;
    const int l15  = lane & 15, q4 = lane >> 4;
    const int wm = (wave >> 1) * 64, wn = (wave & 1) * 64;
    const int m0 = blockIdx.y * 128, n0 = blockIdx.x * 128;
    const int srow = lane >> 3;
    const int scol = ((lane & 7) ^ srow) * 8;

    f32x4 acc[4][4];
    #pragma unroll
    for (int i = 0; i < 4; i++)
        #pragma unroll
        for (int j = 0; j < 4; j++) { f32x4 z = {}; acc[i][j] = z; }

    for (int k0 = 0; k0 < 1024; k0 += 64) {
        __syncthreads();
        #pragma unroll
        for (int i = 0; i < 4; i++) {
            int rb = wave * 32 + i * 8;
            gl_lds16(X + (size_t)(m0 + rb + srow) * 1024 + k0 + scol, As + rb * 64);
            gl_lds16(W + (size_t)(n0 + rb + srow) * 1024 + k0 + scol, Bs + rb * 64);
        }
        __syncthreads();
        #pragma unroll
        for (int ks = 0; ks < 2; ks++) {
            const int ch = (((4 * ks + q4) ^ (l15 & 7)) * 8);
            bf16x8 af[4], bfr[4];
            #pragma unroll
            for (int i = 0; i < 4; i++) {
                af[i]  = *(const bf16x8*)&As[(wm + i * 16 + l15) * 64 + ch];
                bfr[i] = *(const bf16x8*)&Bs[(wn + i * 16 + l15) * 64 + ch];
            }
            #pragma unroll
            for (int mi = 0; mi < 4; mi++)
                #pragma unroll
                for (int ni = 0; ni < 4; ni++)
                    acc[mi][ni] = __builtin_amdgcn_mfma_f32_16x16x32_bf16(
                        af[mi], bfr[ni], acc[mi][ni], 0, 0, 0);
        }
    }

    #pragma unroll
    for (int mi = 0; mi < 4; mi++) {
        #pragma unroll
        for (int r = 0; r < 4; r++) {
            int row = m0 + wm + mi * 16 + q4 * 4 + r;     // global m = b*T + t
            int b = row >> 11, t = row & 2047;
            #pragma unroll
            for (int ni = 0; ni < 4; ni++) {
                int col = n0 + wn + ni * 16 + l15;        // global f in [0,3072)
                float v = acc[mi][ni][r];
                int sec = col >> 10;                      // 0=q 1=k 2=v
                int hh  = (col >> 6) & 15;
                int d   = col & 63;
                if (sec < 2) {
                    float cs = Cos[t * 64 + d];
                    float sn = Sin[t * 64 + d];
                    float partner = acc[mi][ni ^ 2][r];   // col ^ 32, same lane
                    float rot = (d < 32) ? -partner : partner;
                    v = v * cs + rot * sn;
                    u16* dst = (sec == 0) ? Qo : Ko;
                    dst[(((size_t)(b * 16 + hh)) * 2048 + t) * 64 + d] = f2bf(v);
                } else {
                    Vo[(((size_t)(b * 16 + hh)) * 64 + d) * 2048 + t] = f2bf(v);  // [b,h,d,t]
                }
            }
        }
    }
}

// ---------------------------------------------------------------------------
// Kernel 2: causal flash attention, S^T formulation, KV-tile = 128.
// 64 q-rows/block, 4 waves x 16 rows. XCD-aware mapping: xcd=bx&7 owns 4
// heads x all 32 q-tiles (KV working set 2MB -> fits 4MB per-XCD L2); LPT
// (long qt first) within each XCD. Two barriers per 128 kv (vs 4 before),
// one softmax chain per 128 kv. LDS ~49KB -> 3 blocks/CU.
// ---------------------------------------------------------------------------
__global__ __launch_bounds__(256, 3)
void attn_kernel(const u16* __restrict__ Q, const u16* __restrict__ Kg,
                 const u16* __restrict__ Vt, u16* __restrict__ Oh)
{
    __shared__ __align__(16) u16 Ks[128 * 64];    // [kv][d]   8-chunk rows, ^(row&7)
    __shared__ __align__(16) u16 Vs[64 * 128];    // [d][kv]  16-chunk rows, ^(d&15)
    __shared__ __align__(16) __bf16 Ps[4][16][136];

    const int bx = blockIdx.x;
    const int xcd = bx & 7;
    const int i8  = bx >> 3;            // 0..127 per XCD
    const int bh  = xcd * 4 + (i8 & 3); // 4 heads per XCD
    const int qt  = 31 - (i8 >> 2);     // longest q-tiles first (LPT)
    const int b = bh >> 4, h = bh & 15;
    const int tid = threadIdx.x, wave = tid >> 6, lane = tid & 63;
    const int l15 = lane & 15, q4 = lane >> 4;
    const int srow = lane >> 3;
    const int sKcol = ((lane & 7) ^ srow) * 8;

    const size_t head_off = (size_t)bh * 2048 * 64;
    const u16* Qb = Q  + head_off;
    const u16* Kb = Kg + head_off;
    const u16* Vb = Vt + head_off;     // [d][t] per head

    const int qrow0 = qt * 64 + wave * 16;   // this wave's 16 q-rows

    // Q fragments (B operand): B[n=l15][k=q4*8+j+32*ks], pre-scaled by 1/8.
    bf16x8 qf[2];
    #pragma unroll
    for (int ks = 0; ks < 2; ks++) {
        bf16x8 t = *(const bf16x8*)(Qb + (size_t)(qrow0 + l15) * 64 + ks * 32 + q4 * 8);
        #pragma unroll
        for (int j = 0; j < 8; j++) t[j] = (__bf16)((float)t[j] * 0.125f);
        qf[ks] = t;
    }

    bf16x8 ones;
    #pragma unroll
    for (int j = 0; j < 8; j++) ones[j] = (__bf16)1.0f;

    f32x4 o[4];                       // O rows q=qrow0+q4*4+r, cols d=ni*16+l15
    f32x4 ol = {};                    // row-sum accumulator
    float mstq = -1e30f;              // running max for this lane's q (=l15)
    #pragma unroll
    for (int ni = 0; ni < 4; ni++) { f32x4 z = {}; o[ni] = z; }

    const int nkv = (qt >> 1) + 1;     // 128-wide kv tiles (block-uniform)
    for (int it = 0; it < nkv; it++) {
        const int k0 = it * 128;
        __syncthreads();               // protect Ks/Vs from prev iteration reads
        // 32 staging issues (16 K x 8 rows, 16 V x 4 rows); 8 per wave
        #pragma unroll
        for (int i = 0; i < 8; i++) {
            int id = wave * 8 + i;
            if (id < 16) {
                int rb = id * 8;
                gl_lds16(Kb + (size_t)(k0 + rb + srow) * 64 + sKcol, Ks + rb * 64);
            } else {
                int rb = (id - 16) * 4;
                int d  = rb + (lane >> 4);
                int cl = ((lane & 15) ^ (d & 15)) * 8;
                gl_lds16(Vb + (size_t)d * 2048 + k0 + cl, Vs + rb * 128);
            }
        }
        __syncthreads();

        // S^T = K Q^T : st[half][mi][r]: kv = half*64+mi*16+q4*4+r, q = l15
        f32x4 st[2][4];
        #pragma unroll
        for (int hf = 0; hf < 2; hf++)
            #pragma unroll
            for (int mi = 0; mi < 4; mi++) { f32x4 z = {}; st[hf][mi] = z; }
        #pragma unroll
        for (int ks = 0; ks < 2; ks++) {
            const int ch = (((4 * ks + q4) ^ (l15 & 7)) * 8);
            #pragma unroll
            for (int hf = 0; hf < 2; hf++) {
                bf16x8 kf[4];
                #pragma unroll
                for (int mi = 0; mi < 4; mi++)
                    kf[mi] = *(const bf16x8*)&Ks[(hf * 64 + mi * 16 + l15) * 64 + ch];
                #pragma unroll
                for (int mi = 0; mi < 4; mi++)
                    st[hf][mi] = __builtin_amdgcn_mfma_f32_16x16x32_bf16(
                        kf[mi], qf[ks], st[hf][mi], 0, 0, 0);
            }
        }

        // mask (last tile only) + row max: in-reg tree + 2 shuffle stages
        float rm = -1e30f;
        if (it == nkv - 1) {
            const int tq = qrow0 + l15;
            #pragma unroll
            for (int hf = 0; hf < 2; hf++)
                #pragma unroll
                for (int mi = 0; mi < 4; mi++)
                    #pragma unroll
                    for (int r = 0; r < 4; r++) {
                        float v = st[hf][mi][r];
                        if (k0 + hf * 64 + mi * 16 + q4 * 4 + r > tq) v = -1e30f;
                        st[hf][mi][r] = v;
                        rm = fmaxf(rm, v);
                    }
        } else {
            #pragma unroll
            for (int hf = 0; hf < 2; hf++)
                #pragma unroll
                for (int mi = 0; mi < 4; mi++)
                    #pragma unroll
                    for (int r = 0; r < 4; r++)
                        rm = fmaxf(rm, st[hf][mi][r]);
        }
        rm = fmaxf(rm, __shfl_xor(rm, 16, 64));
        rm = fmaxf(rm, __shfl_xor(rm, 32, 64));

        float mnew  = fmaxf(mstq, rm);
        float alpha = __expf(mstq - mnew);
        mstq = mnew;

        // exp + write P^T rows (q = l15) to Ps: 8B stores
        #pragma unroll
        for (int hf = 0; hf < 2; hf++)
            #pragma unroll
            for (int mi = 0; mi < 4; mi++) {
                bf16x4 p4;
                #pragma unroll
                for (int r = 0; r < 4; r++)
                    p4[r] = (__bf16)__expf(st[hf][mi][r] - mnew);
                *(bf16x4*)&Ps[wave][l15][hf * 64 + mi * 16 + q4 * 4] = p4;
            }

        // alpha to row orientation: flat shuffles
        float ar[4];
        #pragma unroll
        for (int r = 0; r < 4; r++)
            ar[r] = __shfl(alpha, q4 * 4 + r, 64);
        #pragma unroll
        for (int ni = 0; ni < 4; ni++)
            #pragma unroll
            for (int r = 0; r < 4; r++)
                o[ni][r] *= ar[r];
        #pragma unroll
        for (int r = 0; r < 4; r++)
            ol[r] *= ar[r];

        // O += P V ; l += P·1  (contraction over kv=128, 4 ks-steps)
        #pragma unroll
        for (int ks = 0; ks < 4; ks++) {
            bf16x8 pa = *(const bf16x8*)&Ps[wave][l15][ks * 32 + q4 * 8];
            bf16x8 vf[4];
            #pragma unroll
            for (int ni = 0; ni < 4; ni++) {
                const int pc = (((ks * 4 + q4) ^ l15) * 8);   // d&15 == l15
                vf[ni] = *(const bf16x8*)&Vs[(ni * 16 + l15) * 128 + pc];
            }
            #pragma unroll
            for (int ni = 0; ni < 4; ni++)
                o[ni] = __builtin_amdgcn_mfma_f32_16x16x32_bf16(pa, vf[ni], o[ni], 0, 0, 0);
            ol = __builtin_amdgcn_mfma_f32_16x16x32_bf16(pa, ones, ol, 0, 0, 0);
        }
    }

    // Epilogue: O / l -> Oh[b,t,h,d] (= [4096,1024] rows)
    #pragma unroll
    for (int r = 0; r < 4; r++) {
        int t = qrow0 + q4 * 4 + r;
        float inv = 1.0f / ol[r];
        #pragma unroll
        for (int ni = 0; ni < 4; ni++) {
            int d = ni * 16 + l15;
            Oh[(((size_t)(b * 2048 + t)) * 16 + h) * 64 + d] = f2bf(o[ni][r] * inv);
        }
    }
}

// ---------------------------------------------------------------------------
// Kernel 3: out = Oh @ w_out^T (M=4096,N=1024,K=1024), fp32 out.
// 128x64 tiles -> 512 blocks (2/CU).
// ---------------------------------------------------------------------------
__global__ __launch_bounds__(256, 2)
void outproj_kernel(const u16* __restrict__ A, const u16* __restrict__ W,
                    float* __restrict__ Cout)
{
    __shared__ __align__(16) u16 As[128 * 64];
    __shared__ __align__(16) u16 Bs[64 * 64];
    const int tid  = threadIdx.x;
    const int lane = tid & 63, wave = tid >> 6;
    const int l15  = lane & 15, q4 = lane >> 4;
    const int wm = (wave >> 1) * 64, wn = (wave & 1) * 32;
    const int m0 = blockIdx.y * 128, n0 = blockIdx.x * 64;
    const int srow = lane >> 3;
    const int scol = ((lane & 7) ^ srow) * 8;

    f32x4 acc[4][2];
    #pragma unroll
    for (int i = 0; i < 4; i++)
        #pragma unroll
        for (int j = 0; j < 2; j++) { f32x4 z = {}; acc[i][j] = z; }

    for (int k0 = 0; k0 < 1024; k0 += 64) {
        __syncthreads();
        #pragma unroll
        for (int i = 0; i < 6; i++) {           // 24 issues: 16 A + 8 B
            int id = wave * 6 + i;
            if (id < 16) {
                int rb = id * 8;
                gl_lds16(A + (size_t)(m0 + rb + srow) * 1024 + k0 + scol, As + rb * 64);
            } else {
                int rb = (id - 16) * 8;
                gl_lds16(W + (size_t)(n0 + rb + srow) * 1024 + k0 + scol, Bs + rb * 64);
            }
        }
        __syncthreads();
        #pragma unroll
        for (int ks = 0; ks < 2; ks++) {
            const int ch = (((4 * ks + q4) ^ (l15 & 7)) * 8);
            bf16x8 af[4], bfr[2];
            #pragma unroll
            for (int i = 0; i < 4; i++)
                af[i] = *(const bf16x8*)&As[(wm + i * 16 + l15) * 64 + ch];
            #pragma unroll
            for (int ni = 0; ni < 2; ni++)
                bfr[ni] = *(const bf16x8*)&Bs[(wn + ni * 16 + l15) * 64 + ch];
            #pragma unroll
            for (int mi = 0; mi < 4; mi++)
                #pragma unroll
                for (int ni = 0; ni < 2; ni++)
                    acc[mi][ni] = __builtin_amdgcn_mfma_f32_16x16x32_bf16(
                        af[mi], bfr[ni], acc[mi][ni], 0, 0, 0);
        }
    }

    #pragma unroll
    for (int mi = 0; mi < 4; mi++)
        #pragma unroll
        for (int r = 0; r < 4; r++) {
            int row = m0 + wm + mi * 16 + q4 * 4 + r;
            #pragma unroll
            for (int ni = 0; ni < 2; ni++) {
                int col = n0 + wn + ni * 16 + l15;
                Cout[(size_t)row * 1024 + col] = acc[mi][ni][r];
            }
        }
}

extern "C" void kernel_launch(void* const* d_in, const int* in_sizes, int n_in,
                              void* d_out, int out_size, void* d_ws, size_t ws_size,
                              hipStream_t stream) {
    (void)in_sizes; (void)n_in; (void)out_size; (void)ws_size;
    const float* x     = (const float*)d_in[0];   // [2,2048,1024] fp32
    const float* cosp  = (const float*)d_in[1];   // [2048,64] fp32
    const float* sinp  = (const float*)d_in[2];   // [2048,64] fp32
    const float* w_qkv = (const float*)d_in[3];   // [3072,1024] fp32
    const float* w_out = (const float*)d_in[4];   // [1024,1024] fp32
    float* out = (float*)d_out;                   // [2,2048,1024] fp32

    const size_t NELEM = (size_t)2 * 2048 * 1024;  // 4,194,304
    // d_out (16.8 MB fp32): Q bf16 in lower half, X bf16 in upper half.
    // Both dead before outproj overwrites all of d_out.
    u16* Q   = (u16*)d_out;            // [b,h,t,d]
    u16* Xb  = (u16*)d_out + NELEM;    // [4096,1024] bf16
    // ws (25.2 MB):
    u16* K   = (u16*)d_ws;             // [b,h,t,d]
    u16* Vt  = K + NELEM;              // [b,h,d,t]
    u16* Oh  = Vt + NELEM;             // [b,t,h,d]
    u16* Wqb = Oh;                     // w_qkv bf16 — dead before attn writes Oh
    u16* Wob = K;                      // w_out bf16 — written after attn (K dead)

    cvt_xw_kernel<<<7168, 256, 0, stream>>>(x, w_qkv, Xb, Wqb);
    qkv_rope_kernel<<<dim3(24, 32), 256, 0, stream>>>(Xb, Wqb, cosp, sinp, Q, K, Vt);
    attn_kernel<<<1024, 256, 0, stream>>>(Q, K, Vt, Oh);
    cvt_w_kernel<<<1024, 256, 0, stream>>>(w_out, Wob);
    outproj_kernel<<<dim3(16, 32), 256, 0, stream>>>(Oh, Wob, out);
}

// Round 9
// 178.329 us; speedup vs baseline: 2.0408x; 1.0677x over previous
//
#include <hip/hip_runtime.h>

typedef unsigned short u16;
typedef __bf16 bf16x8 __attribute__((ext_vector_type(8)));
typedef __bf16 bf16x4 __attribute__((ext_vector_type(4)));
typedef float f32x4 __attribute__((ext_vector_type(4)));

__device__ __forceinline__ u16 f2bf(float f) {
    union { float f; unsigned int i; } v; v.f = f;
    unsigned int x = v.i;
    x += 0x7fffu + ((x >> 16) & 1u);   // round-to-nearest-even
    return (u16)(x >> 16);
}

// Async global->LDS 16B copy. LDS dest is wave-uniform base + lane*16.
__device__ __forceinline__ void gl_lds16(const u16* g, u16* l) {
    __builtin_amdgcn_global_load_lds(
        (const __attribute__((address_space(1))) void*)g,
        (__attribute__((address_space(3))) void*)l, 16, 0, 0);
}

// ---------------------------------------------------------------------------
// cvt: fp32 -> bf16, vectorized.
// ---------------------------------------------------------------------------
__global__ __launch_bounds__(256, 2)
void cvt_xw_kernel(const float* __restrict__ X, const float* __restrict__ Wq,
                   u16* __restrict__ Xb, u16* __restrict__ Wqb)
{
    const int n1 = 4194304 / 4;   // x chunks
    const int n2 = 3145728 / 4;   // w_qkv chunks
    int i = blockIdx.x * 256 + threadIdx.x;
    const int stride = gridDim.x * 256;
    for (; i < n1 + n2; i += stride) {
        float4 v;
        ushort4* dst;
        if (i < n1) { v = ((const float4*)X)[i];       dst = (ushort4*)Xb + i; }
        else        { v = ((const float4*)Wq)[i - n1]; dst = (ushort4*)Wqb + (i - n1); }
        ushort4 o;
        o.x = f2bf(v.x); o.y = f2bf(v.y); o.z = f2bf(v.z); o.w = f2bf(v.w);
        *dst = o;
    }
}

__global__ __launch_bounds__(256, 2)
void cvt_w_kernel(const float* __restrict__ W, u16* __restrict__ Wb)
{
    int i = blockIdx.x * 256 + threadIdx.x;     // 262144 chunks, grid covers exactly
    float4 v = ((const float4*)W)[i];
    ushort4 o;
    o.x = f2bf(v.x); o.y = f2bf(v.y); o.z = f2bf(v.z); o.w = f2bf(v.w);
    ((ushort4*)Wb)[i] = o;
}

// ---------------------------------------------------------------------------
// Kernel 1: qkv = x @ w_qkv^T (M=4096,N=3072,K=1024), bf16 in, RoPE epilogue.
// m97 pattern: global_load_lds 16B staging into unpadded XOR-swizzled LDS.
// V-blocks (n0>=2048) use packed 8B epilogue stores (4 consecutive t / lane).
// ---------------------------------------------------------------------------
__global__ __launch_bounds__(256, 2)
void qkv_rope_kernel(const u16* __restrict__ X, const u16* __restrict__ W,
                     const float* __restrict__ Cos, const float* __restrict__ Sin,
                     u16* __restrict__ Qo, u16* __restrict__ Ko, u16* __restrict__ Vo)
{
    __shared__ __align__(16) u16 As[128 * 64];
    __shared__ __align__(16) u16 Bs[128 * 64];
    const int tid  = threadIdx.x;
    const int lane = tid & 63, wave = tid >> 6;
    const int l15  = lane & 15, q4 = lane >> 4;
    const int wm = (wave >> 1) * 64, wn = (wave & 1) * 64;
    const int m0 = blockIdx.y * 128, n0 = blockIdx.x * 128;
    const int srow = lane >> 3;
    const int scol = ((lane & 7) ^ srow) * 8;

    f32x4 acc[4][4];
    #pragma unroll
    for (int i = 0; i < 4; i++)
        #pragma unroll
        for (int j = 0; j < 4; j++) { f32x4 z = {}; acc[i][j] = z; }

    for (int k0 = 0; k0 < 1024; k0 += 64) {
        __syncthreads();
        #pragma unroll
        for (int i = 0; i < 4; i++) {
            int rb = wave * 32 + i * 8;
            gl_lds16(X + (size_t)(m0 + rb + srow) * 1024 + k0 + scol, As + rb * 64);
            gl_lds16(W + (size_t)(n0 + rb + srow) * 1024 + k0 + scol, Bs + rb * 64);
        }
        __syncthreads();
        #pragma unroll
        for (int ks = 0; ks < 2; ks++) {
            const int ch = (((4 * ks + q4) ^ (l15 & 7)) * 8);
            bf16x8 af[4], bfr[4];
            #pragma unroll
            for (int i = 0; i < 4; i++) {
                af[i]  = *(const bf16x8*)&As[(wm + i * 16 + l15) * 64 + ch];
                bfr[i] = *(const bf16x8*)&Bs[(wn + i * 16 + l15) * 64 + ch];
            }
            #pragma unroll
            for (int mi = 0; mi < 4; mi++)
                #pragma unroll
                for (int ni = 0; ni < 4; ni++)
                    acc[mi][ni] = __builtin_amdgcn_mfma_f32_16x16x32_bf16(
                        af[mi], bfr[ni], acc[mi][ni], 0, 0, 0);
        }
    }

    if (n0 >= 2048) {
        // Pure-V block: packed stores, 4 t-consecutive values per 8B.
        #pragma unroll
        for (int mi = 0; mi < 4; mi++) {
            int t0row = m0 + wm + mi * 16 + q4 * 4;       // global m, 4-aligned
            int b = t0row >> 11, t0 = t0row & 2047;
            #pragma unroll
            for (int ni = 0; ni < 4; ni++) {
                int col = n0 + wn + ni * 16 + l15;
                int hh  = (col >> 6) & 15;
                int d   = col & 63;
                ushort4 pk;
                pk.x = f2bf(acc[mi][ni][0]); pk.y = f2bf(acc[mi][ni][1]);
                pk.z = f2bf(acc[mi][ni][2]); pk.w = f2bf(acc[mi][ni][3]);
                *(ushort4*)&Vo[(((size_t)(b * 16 + hh)) * 64 + d) * 2048 + t0] = pk;
            }
        }
    } else {
        // Q/K block: RoPE epilogue. C/D layout col=lane&15, row=quad*4+reg.
        #pragma unroll
        for (int mi = 0; mi < 4; mi++) {
            #pragma unroll
            for (int r = 0; r < 4; r++) {
                int row = m0 + wm + mi * 16 + q4 * 4 + r;
                int b = row >> 11, t = row & 2047;
                #pragma unroll
                for (int ni = 0; ni < 4; ni++) {
                    int col = n0 + wn + ni * 16 + l15;
                    float v = acc[mi][ni][r];
                    int sec = col >> 10;
                    int hh  = (col >> 6) & 15;
                    int d   = col & 63;
                    float cs = Cos[t * 64 + d];
                    float sn = Sin[t * 64 + d];
                    float partner = acc[mi][ni ^ 2][r];   // col ^ 32, same lane
                    float rot = (d < 32) ? -partner : partner;
                    v = v * cs + rot * sn;
                    u16* dst = (sec == 0) ? Qo : Ko;
                    dst[(((size_t)(b * 16 + hh)) * 2048 + t) * 64 + d] = f2bf(v);
                }
            }
        }
    }
}

// ---------------------------------------------------------------------------
// Kernel 2: causal flash attention, S^T formulation, KV-tile = 128.
// 64 q-rows/block, 4 waves x 16 rows. XCD-aware: xcd=bx&7 owns 4 heads x all
// q-tiles (KV set 2MB fits per-XCD L2); LPT within XCD. LDS ~49KB -> 3/CU.
// ---------------------------------------------------------------------------
__global__ __launch_bounds__(256, 3)
void attn_kernel(const u16* __restrict__ Q, const u16* __restrict__ Kg,
                 const u16* __restrict__ Vt, u16* __restrict__ Oh)
{
    __shared__ __align__(16) u16 Ks[128 * 64];    // [kv][d]   8-chunk rows, ^(row&7)
    __shared__ __align__(16) u16 Vs[64 * 128];    // [d][kv]  16-chunk rows, ^(d&15)
    __shared__ __align__(16) __bf16 Ps[4][16][136];

    const int bx = blockIdx.x;
    const int xcd = bx & 7;
    const int i8  = bx >> 3;            // 0..127 per XCD
    const int bh  = xcd * 4 + (i8 & 3); // 4 heads per XCD
    const int qt  = 31 - (i8 >> 2);     // longest q-tiles first (LPT)
    const int b = bh >> 4, h = bh & 15;
    const int tid = threadIdx.x, wave = tid >> 6, lane = tid & 63;
    const int l15 = lane & 15, q4 = lane >> 4;
    const int srow = lane >> 3;
    const int sKcol = ((lane & 7) ^ srow) * 8;

    const size_t head_off = (size_t)bh * 2048 * 64;
    const u16* Qb = Q  + head_off;
    const u16* Kb = Kg + head_off;
    const u16* Vb = Vt + head_off;     // [d][t] per head

    const int qrow0 = qt * 64 + wave * 16;   // this wave's 16 q-rows

    // Q fragments (B operand): B[n=l15][k=q4*8+j+32*ks], pre-scaled by 1/8.
    bf16x8 qf[2];
    #pragma unroll
    for (int ks = 0; ks < 2; ks++) {
        bf16x8 t = *(const bf16x8*)(Qb + (size_t)(qrow0 + l15) * 64 + ks * 32 + q4 * 8);
        #pragma unroll
        for (int j = 0; j < 8; j++) t[j] = (__bf16)((float)t[j] * 0.125f);
        qf[ks] = t;
    }

    bf16x8 ones;
    #pragma unroll
    for (int j = 0; j < 8; j++) ones[j] = (__bf16)1.0f;

    f32x4 o[4];                       // O rows q=qrow0+q4*4+r, cols d=ni*16+l15
    f32x4 ol = {};                    // row-sum accumulator
    float mstq = -1e30f;              // running max for this lane's q (=l15)
    #pragma unroll
    for (int ni = 0; ni < 4; ni++) { f32x4 z = {}; o[ni] = z; }

    const int nkv = (qt >> 1) + 1;     // 128-wide kv tiles (block-uniform)
    for (int it = 0; it < nkv; it++) {
        const int k0 = it * 128;
        __syncthreads();               // protect Ks/Vs from prev iteration reads
        #pragma unroll
        for (int i = 0; i < 8; i++) {
            int id = wave * 8 + i;
            if (id < 16) {
                int rb = id * 8;
                gl_lds16(Kb + (size_t)(k0 + rb + srow) * 64 + sKcol, Ks + rb * 64);
            } else {
                int rb = (id - 16) * 4;
                int d  = rb + (lane >> 4);
                int cl = ((lane & 15) ^ (d & 15)) * 8;
                gl_lds16(Vb + (size_t)d * 2048 + k0 + cl, Vs + rb * 128);
            }
        }
        __syncthreads();

        // S^T = K Q^T : st[half][mi][r]: kv = half*64+mi*16+q4*4+r, q = l15
        f32x4 st[2][4];
        #pragma unroll
        for (int hf = 0; hf < 2; hf++)
            #pragma unroll
            for (int mi = 0; mi < 4; mi++) { f32x4 z = {}; st[hf][mi] = z; }
        #pragma unroll
        for (int ks = 0; ks < 2; ks++) {
            const int ch = (((4 * ks + q4) ^ (l15 & 7)) * 8);
            #pragma unroll
            for (int hf = 0; hf < 2; hf++) {
                bf16x8 kf[4];
                #pragma unroll
                for (int mi = 0; mi < 4; mi++)
                    kf[mi] = *(const bf16x8*)&Ks[(hf * 64 + mi * 16 + l15) * 64 + ch];
                #pragma unroll
                for (int mi = 0; mi < 4; mi++)
                    st[hf][mi] = __builtin_amdgcn_mfma_f32_16x16x32_bf16(
                        kf[mi], qf[ks], st[hf][mi], 0, 0, 0);
            }
        }

        // mask (last tile only) + row max: in-reg tree + 2 shuffle stages
        float rm = -1e30f;
        if (it == nkv - 1) {
            const int tq = qrow0 + l15;
            #pragma unroll
            for (int hf = 0; hf < 2; hf++)
                #pragma unroll
                for (int mi = 0; mi < 4; mi++)
                    #pragma unroll
                    for (int r = 0; r < 4; r++) {
                        float v = st[hf][mi][r];
                        if (k0 + hf * 64 + mi * 16 + q4 * 4 + r > tq) v = -1e30f;
                        st[hf][mi][r] = v;
                        rm = fmaxf(rm, v);
                    }
        } else {
            #pragma unroll
            for (int hf = 0; hf < 2; hf++)
                #pragma unroll
                for (int mi = 0; mi < 4; mi++)
                    #pragma unroll
                    for (int r = 0; r < 4; r++)
                        rm = fmaxf(rm, st[hf][mi][r]);
        }
        rm = fmaxf(rm, __shfl_xor(rm, 16, 64));
        rm = fmaxf(rm, __shfl_xor(rm, 32, 64));

        float mnew  = fmaxf(mstq, rm);
        float alpha = __expf(mstq - mnew);
        mstq = mnew;

        // exp + write P^T rows (q = l15) to Ps: 8B stores
        #pragma unroll
        for (int hf = 0; hf < 2; hf++)
            #pragma unroll
            for (int mi = 0; mi < 4; mi++) {
                bf16x4 p4;
                #pragma unroll
                for (int r = 0; r < 4; r++)
                    p4[r] = (__bf16)__expf(st[hf][mi][r] - mnew);
                *(bf16x4*)&Ps[wave][l15][hf * 64 + mi * 16 + q4 * 4] = p4;
            }

        // alpha to row orientation: flat shuffles
        float ar[4];
        #pragma unroll
        for (int r = 0; r < 4; r++)
            ar[r] = __shfl(alpha, q4 * 4 + r, 64);
        #pragma unroll
        for (int ni = 0; ni < 4; ni++)
            #pragma unroll
            for (int r = 0; r < 4; r++)
                o[ni][r] *= ar[r];
        #pragma unroll
        for (int r = 0; r < 4; r++)
            ol[r] *= ar[r];

        // O += P V ; l += P·1  (contraction over kv=128, 4 ks-steps)
        #pragma unroll
        for (int ks = 0; ks < 4; ks++) {
            bf16x8 pa = *(const bf16x8*)&Ps[wave][l15][ks * 32 + q4 * 8];
            bf16x8 vf[4];
            #pragma unroll
            for (int ni = 0; ni < 4; ni++) {
                const int pc = (((ks * 4 + q4) ^ l15) * 8);   // d&15 == l15
                vf[ni] = *(const bf16x8*)&Vs[(ni * 16 + l15) * 128 + pc];
            }
            #pragma unroll
            for (int ni = 0; ni < 4; ni++)
                o[ni] = __builtin_amdgcn_mfma_f32_16x16x32_bf16(pa, vf[ni], o[ni], 0, 0, 0);
            ol = __builtin_amdgcn_mfma_f32_16x16x32_bf16(pa, ones, ol, 0, 0, 0);
        }
    }

    // Epilogue: O / l -> Oh[b,t,h,d] (= [4096,1024] rows)
    #pragma unroll
    for (int r = 0; r < 4; r++) {
        int t = qrow0 + q4 * 4 + r;
        float inv = 1.0f / ol[r];
        #pragma unroll
        for (int ni = 0; ni < 4; ni++) {
            int d = ni * 16 + l15;
            Oh[(((size_t)(b * 2048 + t)) * 16 + h) * 64 + d] = f2bf(o[ni][r] * inv);
        }
    }
}

// ---------------------------------------------------------------------------
// Kernel 3: out = Oh @ w_out^T (M=4096,N=1024,K=1024), fp32 out.
// 64x64 tiles, BK=128 -> 1024 blocks = 4/CU = 16 waves/CU. 4 waves as 2x2 of
// 32x32 wave tiles. 16-chunk XOR-swizzled LDS rows (attn-Vs pattern).
// ---------------------------------------------------------------------------
__global__ __launch_bounds__(256, 4)
void outproj_kernel(const u16* __restrict__ A, const u16* __restrict__ W,
                    float* __restrict__ Cout)
{
    __shared__ __align__(16) u16 As[64 * 128];
    __shared__ __align__(16) u16 Bs[64 * 128];
    const int tid  = threadIdx.x;
    const int lane = tid & 63, wave = tid >> 6;
    const int l15  = lane & 15, q4 = lane >> 4;
    const int wm = (wave >> 1) * 32, wn = (wave & 1) * 32;
    const int m0 = blockIdx.y * 64, n0 = blockIdx.x * 64;

    f32x4 acc[2][2];
    #pragma unroll
    for (int i = 0; i < 2; i++)
        #pragma unroll
        for (int j = 0; j < 2; j++) { f32x4 z = {}; acc[i][j] = z; }

    for (int k0 = 0; k0 < 1024; k0 += 128) {
        __syncthreads();
        #pragma unroll
        for (int i = 0; i < 8; i++) {           // 32 issues: 16 A + 16 B, 4-row each
            int id = wave * 8 + i;
            int rb = (id & 15) * 4;
            int row = rb + (lane >> 4);
            int cl  = ((lane & 15) ^ (row & 15)) * 8;
            if (id < 16)
                gl_lds16(A + (size_t)(m0 + row) * 1024 + k0 + cl, As + rb * 128);
            else
                gl_lds16(W + (size_t)(n0 + row) * 1024 + k0 + cl, Bs + rb * 128);
        }
        __syncthreads();
        #pragma unroll
        for (int ks = 0; ks < 4; ks++) {
            const int ch = (((ks * 4 + q4) ^ l15) * 8);
            bf16x8 af[2], bfr[2];
            #pragma unroll
            for (int i = 0; i < 2; i++) {
                af[i]  = *(const bf16x8*)&As[(wm + i * 16 + l15) * 128 + ch];
                bfr[i] = *(const bf16x8*)&Bs[(wn + i * 16 + l15) * 128 + ch];
            }
            #pragma unroll
            for (int mi = 0; mi < 2; mi++)
                #pragma unroll
                for (int ni = 0; ni < 2; ni++)
                    acc[mi][ni] = __builtin_amdgcn_mfma_f32_16x16x32_bf16(
                        af[mi], bfr[ni], acc[mi][ni], 0, 0, 0);
        }
    }

    #pragma unroll
    for (int mi = 0; mi < 2; mi++)
        #pragma unroll
        for (int r = 0; r < 4; r++) {
            int row = m0 + wm + mi * 16 + q4 * 4 + r;
            #pragma unroll
            for (int ni = 0; ni < 2; ni++) {
                int col = n0 + wn + ni * 16 + l15;
                Cout[(size_t)row * 1024 + col] = acc[mi][ni][r];
            }
        }
}

extern "C" void kernel_launch(void* const* d_in, const int* in_sizes, int n_in,
                              void* d_out, int out_size, void* d_ws, size_t ws_size,
                              hipStream_t stream) {
    (void)in_sizes; (void)n_in; (void)out_size; (void)ws_size;
    const float* x     = (const float*)d_in[0];   // [2,2048,1024] fp32
    const float* cosp  = (const float*)d_in[1];   // [2048,64] fp32
    const float* sinp  = (const float*)d_in[2];   // [2048,64] fp32
    const float* w_qkv = (const float*)d_in[3];   // [3072,1024] fp32
    const float* w_out = (const float*)d_in[4];   // [1024,1024] fp32
    float* out = (float*)d_out;                   // [2,2048,1024] fp32

    const size_t NELEM = (size_t)2 * 2048 * 1024;  // 4,194,304
    // d_out (16.8 MB fp32): Q bf16 in lower half, X bf16 in upper half.
    // Both dead before outproj overwrites all of d_out.
    u16* Q   = (u16*)d_out;            // [b,h,t,d]
    u16* Xb  = (u16*)d_out + NELEM;    // [4096,1024] bf16
    // ws (25.2 MB):
    u16* K   = (u16*)d_ws;             // [b,h,t,d]
    u16* Vt  = K + NELEM;              // [b,h,d,t]
    u16* Oh  = Vt + NELEM;             // [b,t,h,d]
    u16* Wqb = Oh;                     // w_qkv bf16 — dead before attn writes Oh
    u16* Wob = K;                      // w_out bf16 — written after attn (K dead)

    cvt_xw_kernel<<<7168, 256, 0, stream>>>(x, w_qkv, Xb, Wqb);
    qkv_rope_kernel<<<dim3(24, 32), 256, 0, stream>>>(Xb, Wqb, cosp, sinp, Q, K, Vt);
    attn_kernel<<<1024, 256, 0, stream>>>(Q, K, Vt, Oh);
    cvt_w_kernel<<<1024, 256, 0, stream>>>(w_out, Wob);
    outproj_kernel<<<dim3(16, 64), 256, 0, stream>>>(Oh, Wob, out);
}

// Round 10
// 172.422 us; speedup vs baseline: 2.1107x; 1.0343x over previous
//
#include <hip/hip_runtime.h>

typedef unsigned short u16;
typedef __bf16 bf16x8 __attribute__((ext_vector_type(8)));
typedef __bf16 bf16x4 __attribute__((ext_vector_type(4)));
typedef float f32x4 __attribute__((ext_vector_type(4)));

__device__ __forceinline__ u16 f2bf(float f) {
    union { float f; unsigned int i; } v; v.f = f;
    unsigned int x = v.i;
    x += 0x7fffu + ((x >> 16) & 1u);   // round-to-nearest-even
    return (u16)(x >> 16);
}

// Async global->LDS 16B copy. LDS dest is wave-uniform base + lane*16.
__device__ __forceinline__ void gl_lds16(const u16* g, u16* l) {
    __builtin_amdgcn_global_load_lds(
        (const __attribute__((address_space(1))) void*)g,
        (__attribute__((address_space(3))) void*)l, 16, 0, 0);
}

// ---------------------------------------------------------------------------
// cvt: fp32 -> bf16, grid-stride. Up to three source ranges in one launch
// (x, w_qkv, and optionally w_out when the workspace has room for it).
// ---------------------------------------------------------------------------
__global__ __launch_bounds__(256, 2)
void cvt_all_kernel(const float* __restrict__ X, const float* __restrict__ Wq,
                    const float* __restrict__ Wo,
                    u16* __restrict__ Xb, u16* __restrict__ Wqb,
                    u16* __restrict__ Wob, int n3)
{
    const int n1 = 4194304 / 4;   // x chunks
    const int n2 = 3145728 / 4;   // w_qkv chunks
    int i = blockIdx.x * 256 + threadIdx.x;
    const int stride = gridDim.x * 256;
    for (; i < n1 + n2 + n3; i += stride) {
        float4 v;
        ushort4* dst;
        if (i < n1)           { v = ((const float4*)X)[i];            dst = (ushort4*)Xb  + i; }
        else if (i < n1 + n2) { v = ((const float4*)Wq)[i - n1];      dst = (ushort4*)Wqb + (i - n1); }
        else                  { v = ((const float4*)Wo)[i - n1 - n2]; dst = (ushort4*)Wob + (i - n1 - n2); }
        ushort4 o;
        o.x = f2bf(v.x); o.y = f2bf(v.y); o.z = f2bf(v.z); o.w = f2bf(v.w);
        *dst = o;
    }
}

__global__ __launch_bounds__(256, 2)
void cvt_w_kernel(const float* __restrict__ W, u16* __restrict__ Wb)
{
    int i = blockIdx.x * 256 + threadIdx.x;     // 262144 chunks, grid covers exactly
    float4 v = ((const float4*)W)[i];
    ushort4 o;
    o.x = f2bf(v.x); o.y = f2bf(v.y); o.z = f2bf(v.z); o.w = f2bf(v.w);
    ((ushort4*)Wb)[i] = o;
}

// ---------------------------------------------------------------------------
// Kernel 1: qkv = x @ w_qkv^T (M=4096,N=3072,K=1024), bf16 in, RoPE epilogue.
// m97 pattern: global_load_lds 16B staging into unpadded XOR-swizzled LDS.
// V-blocks (n0>=2048) use packed 8B epilogue stores (4 consecutive t / lane).
// ---------------------------------------------------------------------------
__global__ __launch_bounds__(256, 2)
void qkv_rope_kernel(const u16* __restrict__ X, const u16* __restrict__ W,
                     const float* __restrict__ Cos, const float* __restrict__ Sin,
                     u16* __restrict__ Qo, u16* __restrict__ Ko, u16* __restrict__ Vo)
{
    __shared__ __align__(16) u16 As[128 * 64];
    __shared__ __align__(16) u16 Bs[128 * 64];
    const int tid  = threadIdx.x;
    const int lane = tid & 63, wave = tid >> 6;
    const int l15  = lane & 15, q4 = lane >> 4;
    const int wm = (wave >> 1) * 64, wn = (wave & 1) * 64;
    const int m0 = blockIdx.y * 128, n0 = blockIdx.x * 128;
    const int srow = lane >> 3;
    const int scol = ((lane & 7) ^ srow) * 8;

    f32x4 acc[4][4];
    #pragma unroll
    for (int i = 0; i < 4; i++)
        #pragma unroll
        for (int j = 0; j < 4; j++) { f32x4 z = {}; acc[i][j] = z; }

    for (int k0 = 0; k0 < 1024; k0 += 64) {
        __syncthreads();
        #pragma unroll
        for (int i = 0; i < 4; i++) {
            int rb = wave * 32 + i * 8;
            gl_lds16(X + (size_t)(m0 + rb + srow) * 1024 + k0 + scol, As + rb * 64);
            gl_lds16(W + (size_t)(n0 + rb + srow) * 1024 + k0 + scol, Bs + rb * 64);
        }
        __syncthreads();
        #pragma unroll
        for (int ks = 0; ks < 2; ks++) {
            const int ch = (((4 * ks + q4) ^ (l15 & 7)) * 8);
            bf16x8 af[4], bfr[4];
            #pragma unroll
            for (int i = 0; i < 4; i++) {
                af[i]  = *(const bf16x8*)&As[(wm + i * 16 + l15) * 64 + ch];
                bfr[i] = *(const bf16x8*)&Bs[(wn + i * 16 + l15) * 64 + ch];
            }
            #pragma unroll
            for (int mi = 0; mi < 4; mi++)
                #pragma unroll
                for (int ni = 0; ni < 4; ni++)
                    acc[mi][ni] = __builtin_amdgcn_mfma_f32_16x16x32_bf16(
                        af[mi], bfr[ni], acc[mi][ni], 0, 0, 0);
        }
    }

    if (n0 >= 2048) {
        // Pure-V block: packed stores, 4 t-consecutive values per 8B.
        #pragma unroll
        for (int mi = 0; mi < 4; mi++) {
            int t0row = m0 + wm + mi * 16 + q4 * 4;       // global m, 4-aligned
            int b = t0row >> 11, t0 = t0row & 2047;
            #pragma unroll
            for (int ni = 0; ni < 4; ni++) {
                int col = n0 + wn + ni * 16 + l15;
                int hh  = (col >> 6) & 15;
                int d   = col & 63;
                ushort4 pk;
                pk.x = f2bf(acc[mi][ni][0]); pk.y = f2bf(acc[mi][ni][1]);
                pk.z = f2bf(acc[mi][ni][2]); pk.w = f2bf(acc[mi][ni][3]);
                *(ushort4*)&Vo[(((size_t)(b * 16 + hh)) * 64 + d) * 2048 + t0] = pk;
            }
        }
    } else {
        // Q/K block: RoPE epilogue. C/D layout col=lane&15, row=quad*4+reg.
        #pragma unroll
        for (int mi = 0; mi < 4; mi++) {
            #pragma unroll
            for (int r = 0; r < 4; r++) {
                int row = m0 + wm + mi * 16 + q4 * 4 + r;
                int b = row >> 11, t = row & 2047;
                #pragma unroll
                for (int ni = 0; ni < 4; ni++) {
                    int col = n0 + wn + ni * 16 + l15;
                    float v = acc[mi][ni][r];
                    int sec = col >> 10;
                    int hh  = (col >> 6) & 15;
                    int d   = col & 63;
                    float cs = Cos[t * 64 + d];
                    float sn = Sin[t * 64 + d];
                    float partner = acc[mi][ni ^ 2][r];   // col ^ 32, same lane
                    float rot = (d < 32) ? -partner : partner;
                    v = v * cs + rot * sn;
                    u16* dst = (sec == 0) ? Qo : Ko;
                    dst[(((size_t)(b * 16 + hh)) * 2048 + t) * 64 + d] = f2bf(v);
                }
            }
        }
    }
}

// ---------------------------------------------------------------------------
// Kernel 2: causal flash attention, S^T formulation, KV-tile = 128.
// exp2-domain softmax (Q pre-scaled by 0.125*log2e in fp32); split staging:
// K -> barrier -> issue V -> S + softmax overlap V loads -> barrier -> PV.
// XCD-aware: xcd=bx&7 owns 4 heads; LPT within XCD. LDS ~49KB -> 3/CU.
// ---------------------------------------------------------------------------
__global__ __launch_bounds__(256, 3)
void attn_kernel(const u16* __restrict__ Q, const u16* __restrict__ Kg,
                 const u16* __restrict__ Vt, u16* __restrict__ Oh)
{
    __shared__ __align__(16) u16 Ks[128 * 64];    // [kv][d]   8-chunk rows, ^(row&7)
    __shared__ __align__(16) u16 Vs[64 * 128];    // [d][kv]  16-chunk rows, ^(d&15)
    __shared__ __align__(16) __bf16 Ps[4][16][136];

    const int bx = blockIdx.x;
    const int xcd = bx & 7;
    const int i8  = bx >> 3;            // 0..127 per XCD
    const int bh  = xcd * 4 + (i8 & 3); // 4 heads per XCD
    const int qt  = 31 - (i8 >> 2);     // longest q-tiles first (LPT)
    const int b = bh >> 4, h = bh & 15;
    const int tid = threadIdx.x, wave = tid >> 6, lane = tid & 63;
    const int l15 = lane & 15, q4 = lane >> 4;
    const int srow = lane >> 3;
    const int sKcol = ((lane & 7) ^ srow) * 8;

    const size_t head_off = (size_t)bh * 2048 * 64;
    const u16* Qb = Q  + head_off;
    const u16* Kb = Kg + head_off;
    const u16* Vb = Vt + head_off;     // [d][t] per head

    const int qrow0 = qt * 64 + wave * 16;   // this wave's 16 q-rows

    // Q fragments (B operand): B[n=l15][k=q4*8+j+32*ks].
    // Pre-scale by 0.125*log2(e): softmax moves to exp2 domain (exact
    // monotone transform; scaling done in fp32, rounding unbiased).
    const float QSCALE = 0.18033688f;
    bf16x8 qf[2];
    #pragma unroll
    for (int ks = 0; ks < 2; ks++) {
        bf16x8 t = *(const bf16x8*)(Qb + (size_t)(qrow0 + l15) * 64 + ks * 32 + q4 * 8);
        #pragma unroll
        for (int j = 0; j < 8; j++) t[j] = (__bf16)((float)t[j] * QSCALE);
        qf[ks] = t;
    }

    bf16x8 ones;
    #pragma unroll
    for (int j = 0; j < 8; j++) ones[j] = (__bf16)1.0f;

    f32x4 o[4];                       // O rows q=qrow0+q4*4+r, cols d=ni*16+l15
    f32x4 ol = {};                    // row-sum accumulator
    float mstq = -1e30f;              // running max (log2 domain), lane's q=l15
    #pragma unroll
    for (int ni = 0; ni < 4; ni++) { f32x4 z = {}; o[ni] = z; }

    const int nkv = (qt >> 1) + 1;     // 128-wide kv tiles (block-uniform)
    for (int it = 0; it < nkv; it++) {
        const int k0 = it * 128;
        __syncthreads();               // Ks/Vs free of prev-iter readers
        #pragma unroll
        for (int i = 0; i < 4; i++) {  // K: 16 row-block issues, 4/wave
            int rb = (wave * 4 + i) * 8;
            gl_lds16(Kb + (size_t)(k0 + rb + srow) * 64 + sKcol, Ks + rb * 64);
        }
        __syncthreads();               // K ready (drains this wave's K loads)
        #pragma unroll
        for (int i = 0; i < 4; i++) {  // V: 16 issues, in flight through S phase
            int rb = (wave * 4 + i) * 4;
            int d  = rb + (lane >> 4);
            int cl = ((lane & 15) ^ (d & 15)) * 8;
            gl_lds16(Vb + (size_t)d * 2048 + k0 + cl, Vs + rb * 128);
        }

        // S^T = K Q^T : st[half][mi][r]: kv = half*64+mi*16+q4*4+r, q = l15
        f32x4 st[2][4];
        #pragma unroll
        for (int hf = 0; hf < 2; hf++)
            #pragma unroll
            for (int mi = 0; mi < 4; mi++) { f32x4 z = {}; st[hf][mi] = z; }
        #pragma unroll
        for (int ks = 0; ks < 2; ks++) {
            const int ch = (((4 * ks + q4) ^ (l15 & 7)) * 8);
            #pragma unroll
            for (int hf = 0; hf < 2; hf++) {
                bf16x8 kf[4];
                #pragma unroll
                for (int mi = 0; mi < 4; mi++)
                    kf[mi] = *(const bf16x8*)&Ks[(hf * 64 + mi * 16 + l15) * 64 + ch];
                #pragma unroll
                for (int mi = 0; mi < 4; mi++)
                    st[hf][mi] = __builtin_amdgcn_mfma_f32_16x16x32_bf16(
                        kf[mi], qf[ks], st[hf][mi], 0, 0, 0);
            }
        }

        // mask (last tile only) + row max: in-reg tree + 2 shuffle stages
        float rm = -1e30f;
        if (it == nkv - 1) {
            const int tq = qrow0 + l15;
            #pragma unroll
            for (int hf = 0; hf < 2; hf++)
                #pragma unroll
                for (int mi = 0; mi < 4; mi++)
                    #pragma unroll
                    for (int r = 0; r < 4; r++) {
                        float v = st[hf][mi][r];
                        if (k0 + hf * 64 + mi * 16 + q4 * 4 + r > tq) v = -1e30f;
                        st[hf][mi][r] = v;
                        rm = fmaxf(rm, v);
                    }
        } else {
            #pragma unroll
            for (int hf = 0; hf < 2; hf++)
                #pragma unroll
                for (int mi = 0; mi < 4; mi++)
                    #pragma unroll
                    for (int r = 0; r < 4; r++)
                        rm = fmaxf(rm, st[hf][mi][r]);
        }
        rm = fmaxf(rm, __shfl_xor(rm, 16, 64));
        rm = fmaxf(rm, __shfl_xor(rm, 32, 64));

        float mnew  = fmaxf(mstq, rm);
        float alpha = exp2f(mstq - mnew);
        mstq = mnew;

        // exp2 + write P^T rows (q = l15) to Ps: 8B stores
        #pragma unroll
        for (int hf = 0; hf < 2; hf++)
            #pragma unroll
            for (int mi = 0; mi < 4; mi++) {
                bf16x4 p4;
                #pragma unroll
                for (int r = 0; r < 4; r++)
                    p4[r] = (__bf16)exp2f(st[hf][mi][r] - mnew);
                *(bf16x4*)&Ps[wave][l15][hf * 64 + mi * 16 + q4 * 4] = p4;
            }

        // alpha to row orientation: flat shuffles
        float ar[4];
        #pragma unroll
        for (int r = 0; r < 4; r++)
            ar[r] = __shfl(alpha, q4 * 4 + r, 64);
        #pragma unroll
        for (int ni = 0; ni < 4; ni++)
            #pragma unroll
            for (int r = 0; r < 4; r++)
                o[ni][r] *= ar[r];
        #pragma unroll
        for (int r = 0; r < 4; r++)
            ol[r] *= ar[r];

        __syncthreads();               // V ready (drains V loads block-wide)

        // O += P V ; l += P·1  (contraction over kv=128, 4 ks-steps)
        #pragma unroll
        for (int ks = 0; ks < 4; ks++) {
            bf16x8 pa = *(const bf16x8*)&Ps[wave][l15][ks * 32 + q4 * 8];
            bf16x8 vf[4];
            #pragma unroll
            for (int ni = 0; ni < 4; ni++) {
                const int pc = (((ks * 4 + q4) ^ l15) * 8);   // d&15 == l15
                vf[ni] = *(const bf16x8*)&Vs[(ni * 16 + l15) * 128 + pc];
            }
            #pragma unroll
            for (int ni = 0; ni < 4; ni++)
                o[ni] = __builtin_amdgcn_mfma_f32_16x16x32_bf16(pa, vf[ni], o[ni], 0, 0, 0);
            ol = __builtin_amdgcn_mfma_f32_16x16x32_bf16(pa, ones, ol, 0, 0, 0);
        }
    }

    // Epilogue: O / l -> Oh[b,t,h,d] (= [4096,1024] rows)
    #pragma unroll
    for (int r = 0; r < 4; r++) {
        int t = qrow0 + q4 * 4 + r;
        float inv = 1.0f / ol[r];
        #pragma unroll
        for (int ni = 0; ni < 4; ni++) {
            int d = ni * 16 + l15;
            Oh[(((size_t)(b * 2048 + t)) * 16 + h) * 64 + d] = f2bf(o[ni][r] * inv);
        }
    }
}

// ---------------------------------------------------------------------------
// Kernel 3: out = Oh @ w_out^T (M=4096,N=1024,K=1024), fp32 out.
// 64x64 tiles, BK=128 -> 1024 blocks = 4/CU = 16 waves/CU.
// ---------------------------------------------------------------------------
__global__ __launch_bounds__(256, 4)
void outproj_kernel(const u16* __restrict__ A, const u16* __restrict__ W,
                    float* __restrict__ Cout)
{
    __shared__ __align__(16) u16 As[64 * 128];
    __shared__ __align__(16) u16 Bs[64 * 128];
    const int tid  = threadIdx.x;
    const int lane = tid & 63, wave = tid >> 6;
    const int l15  = lane & 15, q4 = lane >> 4;
    const int wm = (wave >> 1) * 32, wn = (wave & 1) * 32;
    const int m0 = blockIdx.y * 64, n0 = blockIdx.x * 64;

    f32x4 acc[2][2];
    #pragma unroll
    for (int i = 0; i < 2; i++)
        #pragma unroll
        for (int j = 0; j < 2; j++) { f32x4 z = {}; acc[i][j] = z; }

    for (int k0 = 0; k0 < 1024; k0 += 128) {
        __syncthreads();
        #pragma unroll
        for (int i = 0; i < 8; i++) {           // 32 issues: 16 A + 16 B, 4-row each
            int id = wave * 8 + i;
            int rb = (id & 15) * 4;
            int row = rb + (lane >> 4);
            int cl  = ((lane & 15) ^ (row & 15)) * 8;
            if (id < 16)
                gl_lds16(A + (size_t)(m0 + row) * 1024 + k0 + cl, As + rb * 128);
            else
                gl_lds16(W + (size_t)(n0 + row) * 1024 + k0 + cl, Bs + rb * 128);
        }
        __syncthreads();
        #pragma unroll
        for (int ks = 0; ks < 4; ks++) {
            const int ch = (((ks * 4 + q4) ^ l15) * 8);
            bf16x8 af[2], bfr[2];
            #pragma unroll
            for (int i = 0; i < 2; i++) {
                af[i]  = *(const bf16x8*)&As[(wm + i * 16 + l15) * 128 + ch];
                bfr[i] = *(const bf16x8*)&Bs[(wn + i * 16 + l15) * 128 + ch];
            }
            #pragma unroll
            for (int mi = 0; mi < 2; mi++)
                #pragma unroll
                for (int ni = 0; ni < 2; ni++)
                    acc[mi][ni] = __builtin_amdgcn_mfma_f32_16x16x32_bf16(
                        af[mi], bfr[ni], acc[mi][ni], 0, 0, 0);
        }
    }

    #pragma unroll
    for (int mi = 0; mi < 2; mi++)
        #pragma unroll
        for (int r = 0; r < 4; r++) {
            int row = m0 + wm + mi * 16 + q4 * 4 + r;
            #pragma unroll
            for (int ni = 0; ni < 2; ni++) {
                int col = n0 + wn + ni * 16 + l15;
                Cout[(size_t)row * 1024 + col] = acc[mi][ni][r];
            }
        }
}

extern "C" void kernel_launch(void* const* d_in, const int* in_sizes, int n_in,
                              void* d_out, int out_size, void* d_ws, size_t ws_size,
                              hipStream_t stream) {
    (void)in_sizes; (void)n_in; (void)out_size;
    const float* x     = (const float*)d_in[0];   // [2,2048,1024] fp32
    const float* cosp  = (const float*)d_in[1];   // [2048,64] fp32
    const float* sinp  = (const float*)d_in[2];   // [2048,64] fp32
    const float* w_qkv = (const float*)d_in[3];   // [3072,1024] fp32
    const float* w_out = (const float*)d_in[4];   // [1024,1024] fp32
    float* out = (float*)d_out;                   // [2,2048,1024] fp32

    const size_t NELEM = (size_t)2 * 2048 * 1024;  // 4,194,304
    // d_out (16.8 MB fp32): Q bf16 in lower half, X bf16 in upper half.
    // Both dead before outproj overwrites all of d_out.
    u16* Q   = (u16*)d_out;            // [b,h,t,d]
    u16* Xb  = (u16*)d_out + NELEM;    // [4096,1024] bf16
    // ws: K 8MB | Vt 8MB | Oh 8MB (+ Wqb aliasing Oh) [+ Wob @24MB if room]
    u16* K   = (u16*)d_ws;             // [b,h,t,d]
    u16* Vt  = K + NELEM;              // [b,h,d,t]
    u16* Oh  = Vt + NELEM;             // [b,t,h,d]
    u16* Wqb = Oh;                     // w_qkv bf16 — dead before attn writes Oh

    const bool big = ws_size >= (24u * 1024 * 1024 + 2u * 1024 * 1024);
    if (big) {
        u16* Wob = K + 3 * NELEM;      // own slot at ws+24MB (2MB)
        cvt_all_kernel<<<7168, 256, 0, stream>>>(x, w_qkv, w_out, Xb, Wqb, Wob,
                                                 262144);
        qkv_rope_kernel<<<dim3(24, 32), 256, 0, stream>>>(Xb, Wqb, cosp, sinp, Q, K, Vt);
        attn_kernel<<<1024, 256, 0, stream>>>(Q, K, Vt, Oh);
        outproj_kernel<<<dim3(16, 64), 256, 0, stream>>>(Oh, Wob, out);
    } else {
        u16* Wob = K;                  // w_out bf16 — written after attn (K dead)
        cvt_all_kernel<<<7168, 256, 0, stream>>>(x, w_qkv, w_out, Xb, Wqb, Wob, 0);
        qkv_rope_kernel<<<dim3(24, 32), 256, 0, stream>>>(Xb, Wqb, cosp, sinp, Q, K, Vt);
        attn_kernel<<<1024, 256, 0, stream>>>(Q, K, Vt, Oh);
        cvt_w_kernel<<<1024, 256, 0, stream>>>(w_out, Wob);
        outproj_kernel<<<dim3(16, 64), 256, 0, stream>>>(Oh, Wob, out);
    }
}